// Round 9
// baseline (464.589 us; speedup 1.0000x reference)
//
#include <hip/hip_runtime.h>

// ---------- types & helpers ----------
typedef float  f32x4 __attribute__((ext_vector_type(4)));
typedef short  short8 __attribute__((ext_vector_type(8)));

__device__ __forceinline__ unsigned short f2bf(float f) {
    unsigned u = __builtin_bit_cast(unsigned, f);
    unsigned r = u + 0x7FFFu + ((u >> 16) & 1u);
    return (unsigned short)(r >> 16);
}
__device__ __forceinline__ float bf2f(unsigned short b) {
    return __builtin_bit_cast(float, (unsigned)b << 16);
}

__device__ __forceinline__ f32x4 mfma16(short8 a, short8 b, f32x4 c) {
    return __builtin_amdgcn_mfma_f32_16x16x32_bf16(a, b, c, 0, 0, 0);
}

#define GLOAD16(gp, lp) \
    __builtin_amdgcn_global_load_lds((const __attribute__((address_space(1))) unsigned int*)(gp), \
                                     (__attribute__((address_space(3))) unsigned int*)(lp), 16, 0, 0)

// ---------- constants ----------
#define BT   4096
#define NTOK 16
#define DDIM 512
#define Y_ELEMS 33554432ULL        // BT*NTOK*DDIM
#define XS_STRIDE 516

// ---------- weight transpose fp32 [R][C] -> bf16 [C][R] ----------
__global__ __launch_bounds__(256) void transpose_kernel(const float* __restrict__ in,
                                                        unsigned short* __restrict__ out,
                                                        int R, int C) {
    __shared__ float tile[32][33];
    const int tx = threadIdx.x & 31, ty = threadIdx.x >> 5;
    const int c0 = blockIdx.x * 32, r0 = blockIdx.y * 32;
#pragma unroll
    for (int i = 0; i < 4; ++i)
        tile[ty + 8 * i][tx] = in[(size_t)(r0 + ty + 8 * i) * C + c0 + tx];
    __syncthreads();
#pragma unroll
    for (int i = 0; i < 4; ++i)
        out[(size_t)(c0 + ty + 8 * i) * R + r0 + tx] = f2bf(tile[tx][ty + 8 * i]);
}

// ---------- mask dtype detection ----------
__global__ void detect_kernel(const unsigned char* __restrict__ m, int* __restrict__ flag) {
    __shared__ int any;
    if (threadIdx.x == 0) any = 0;
    __syncthreads();
    int loc = 0;
    for (int i = threadIdx.x; i < 4096; i += 256)
        if (i & 3) loc |= m[i];
    if (loc) atomicOr(&any, 1);
    __syncthreads();
    if (threadIdx.x == 0) *flag = any ? 1 : 0;
}

// ---------- stage 1 (pure fp32): scores, softmax, p@x, LN1 -> h (bf16 only) ----------
__global__ __launch_bounds__(256) void stage1_kernel(
    const float* __restrict__ x,
    const unsigned char* __restrict__ mask_u8, const int* __restrict__ mask_i32,
    const int* __restrict__ flagp,
    const float* __restrict__ g1, const float* __restrict__ b1,
    float* __restrict__ attn_out, unsigned short* __restrict__ hbf) {
    __shared__ float xs[NTOK * XS_STRIDE];
    __shared__ float p_lds[256];

    const int b = blockIdx.x, t = threadIdx.x;
    const float* xb = x + (size_t)b * (NTOK * DDIM);

#pragma unroll
    for (int i = 0; i < 8; ++i) {
        int s = t + 256 * i;
        int r = s >> 7, c4 = s & 127;
        f32x4 v = ((const f32x4*)xb)[s];
        *(f32x4*)(&xs[r * XS_STRIDE + c4 * 4]) = v;
    }
    __syncthreads();

    const int r = t >> 4, c = t & 15;
    {
        const f32x4* xr = (const f32x4*)(&xs[r * XS_STRIDE]);
        const f32x4* xc = (const f32x4*)(&xs[c * XS_STRIDE]);
        f32x4 d4 = {0.f, 0.f, 0.f, 0.f};
#pragma unroll 8
        for (int u = 0; u < 128; ++u) d4 += xr[u] * xc[u];
        float s_rc = (d4.x + d4.y + d4.z + d4.w) * 0.04419417382415922f;

        const int flag = *flagp;
        size_t midx = (size_t)b * 256 + t;
        bool msk = flag ? (mask_u8[midx] != 0) : (mask_i32[midx] != 0);
        float sv = msk ? -1e30f : s_rc;
        float mx = sv;
        mx = fmaxf(mx, __shfl_xor(mx, 1, 16));
        mx = fmaxf(mx, __shfl_xor(mx, 2, 16));
        mx = fmaxf(mx, __shfl_xor(mx, 4, 16));
        mx = fmaxf(mx, __shfl_xor(mx, 8, 16));
        float e = msk ? 0.f : expf(sv - mx);
        float sum = e;
        sum += __shfl_xor(sum, 1, 16);
        sum += __shfl_xor(sum, 2, 16);
        sum += __shfl_xor(sum, 4, 16);
        sum += __shfl_xor(sum, 8, 16);
        float p = e / sum;
        p_lds[t] = p;
        attn_out[midx] = p;
    }
    __syncthreads();

    const int r2 = t >> 4, tc = t & 15;
    f32x4 acc[8];
#pragma unroll
    for (int j = 0; j < 8; ++j) acc[j] = (f32x4){0.f, 0.f, 0.f, 0.f};
    for (int c2 = 0; c2 < 16; ++c2) {
        float pw = p_lds[r2 * 16 + c2];
        const f32x4* xrow = (const f32x4*)(&xs[c2 * XS_STRIDE]);
#pragma unroll
        for (int j = 0; j < 8; ++j) acc[j] += pw * xrow[tc + 16 * j];
    }

    const f32x4* xme = (const f32x4*)(&xs[r2 * XS_STRIDE]);
    f32x4 vv[8];
    float s1 = 0.f, s2 = 0.f;
#pragma unroll
    for (int j = 0; j < 8; ++j) {
        f32x4 v = xme[tc + 16 * j] + acc[j];
        vv[j] = v;
        s1 += v.x + v.y + v.z + v.w;
        s2 += v.x * v.x + v.y * v.y + v.z * v.z + v.w * v.w;
    }
    s1 += __shfl_xor(s1, 1, 16); s2 += __shfl_xor(s2, 1, 16);
    s1 += __shfl_xor(s1, 2, 16); s2 += __shfl_xor(s2, 2, 16);
    s1 += __shfl_xor(s1, 4, 16); s2 += __shfl_xor(s2, 4, 16);
    s1 += __shfl_xor(s1, 8, 16); s2 += __shfl_xor(s2, 8, 16);
    float mu = s1 * (1.f / 512.f);
    float var = s2 * (1.f / 512.f) - mu * mu;
    float inv = rsqrtf(var + 1e-5f);

    unsigned short* hrow = hbf + (size_t)(b * NTOK + r2) * DDIM;
#pragma unroll
    for (int j = 0; j < 8; ++j) {
        int u = tc + 16 * j;
        f32x4 gv = ((const f32x4*)g1)[u];
        f32x4 bv = ((const f32x4*)b1)[u];
        f32x4 o = (vv[j] - mu) * inv * gv + bv;
        uint2 pk;
        pk.x = (unsigned)f2bf(o.x) | ((unsigned)f2bf(o.y) << 16);
        pk.y = (unsigned)f2bf(o.z) | ((unsigned)f2bf(o.w) << 16);
        *(uint2*)(hrow + u * 4) = pk;
    }
}

// ---------- FFN1: 8-phase 256x256 GEMM, one barrier per phase (round-8 proven) ----------
#define PH_READA(Al, Q) { short8 a00, a01, a10, a11; \
    a00 = *(const short8*)((Al) + aoffs[2*(Q)]   + kk2[0]); \
    a01 = *(const short8*)((Al) + aoffs[2*(Q)]   + kk2[1]); \
    a10 = *(const short8*)((Al) + aoffs[2*(Q)+1] + kk2[0]); \
    a11 = *(const short8*)((Al) + aoffs[2*(Q)+1] + kk2[1]);

#define PH_READB(Bl) \
    bb00 = *(const short8*)((Bl) + boffs[0] + kk2[0]); \
    bb01 = *(const short8*)((Bl) + boffs[0] + kk2[1]); \
    bb10 = *(const short8*)((Bl) + boffs[1] + kk2[0]); \
    bb11 = *(const short8*)((Bl) + boffs[1] + kk2[1]); \
    bb20 = *(const short8*)((Bl) + boffs[2] + kk2[0]); \
    bb21 = *(const short8*)((Bl) + boffs[2] + kk2[1]); \
    bb30 = *(const short8*)((Bl) + boffs[3] + kk2[0]); \
    bb31 = *(const short8*)((Bl) + boffs[3] + kk2[1]);

#define PH_MFMA(Q) \
    asm volatile("s_waitcnt lgkmcnt(0)" ::: "memory"); \
    __builtin_amdgcn_sched_barrier(0); \
    __builtin_amdgcn_s_setprio(1); \
    acc[2*(Q)][0]   = mfma16(a00, bb00, acc[2*(Q)][0]); \
    acc[2*(Q)][0]   = mfma16(a01, bb01, acc[2*(Q)][0]); \
    acc[2*(Q)][1]   = mfma16(a00, bb10, acc[2*(Q)][1]); \
    acc[2*(Q)][1]   = mfma16(a01, bb11, acc[2*(Q)][1]); \
    acc[2*(Q)][2]   = mfma16(a00, bb20, acc[2*(Q)][2]); \
    acc[2*(Q)][2]   = mfma16(a01, bb21, acc[2*(Q)][2]); \
    acc[2*(Q)][3]   = mfma16(a00, bb30, acc[2*(Q)][3]); \
    acc[2*(Q)][3]   = mfma16(a01, bb31, acc[2*(Q)][3]); \
    acc[2*(Q)+1][0] = mfma16(a10, bb00, acc[2*(Q)+1][0]); \
    acc[2*(Q)+1][0] = mfma16(a11, bb01, acc[2*(Q)+1][0]); \
    acc[2*(Q)+1][1] = mfma16(a10, bb10, acc[2*(Q)+1][1]); \
    acc[2*(Q)+1][1] = mfma16(a11, bb11, acc[2*(Q)+1][1]); \
    acc[2*(Q)+1][2] = mfma16(a10, bb20, acc[2*(Q)+1][2]); \
    acc[2*(Q)+1][2] = mfma16(a11, bb21, acc[2*(Q)+1][2]); \
    acc[2*(Q)+1][3] = mfma16(a10, bb30, acc[2*(Q)+1][3]); \
    acc[2*(Q)+1][3] = mfma16(a11, bb31, acc[2*(Q)+1][3]); \
    __builtin_amdgcn_s_setprio(0);

#define PH_END  __builtin_amdgcn_s_barrier(); }

#define GEMM_BODY(MORE) \
        PH_READA(A0lds, 0) PH_READB(B0lds) \
        stageA(v, A1lds, 0); stageA(v, A1lds, 1); \
        PH_MFMA(0) PH_END \
        PH_READA(A0lds, 1) \
        if (MORE) stageB(u2, B0lds, 0); \
        PH_MFMA(1) PH_END \
        PH_READA(A0lds, 2) \
        if (MORE) stageB(u2, B0lds, 1); \
        PH_MFMA(2) PH_END \
        PH_READA(A0lds, 3) \
        PH_MFMA(3) \
        if (MORE) { asm volatile("s_waitcnt vmcnt(4)" ::: "memory"); } \
        else      { asm volatile("s_waitcnt vmcnt(0)" ::: "memory"); } \
        PH_END \
        PH_READA(A1lds, 0) PH_READB(B1lds) \
        if (MORE) stageA(u2, A0lds, 0); \
        PH_MFMA(0) PH_END \
        PH_READA(A1lds, 1) \
        if (MORE) stageA(u2, A0lds, 1); \
        PH_MFMA(1) PH_END \
        PH_READA(A1lds, 2) \
        if (MORE) stageB(v2, B1lds, 0); \
        PH_MFMA(2) PH_END \
        PH_READA(A1lds, 3) \
        if (MORE) stageB(v2, B1lds, 1); \
        PH_MFMA(3) \
        if (MORE) { asm volatile("s_waitcnt vmcnt(4)" ::: "memory"); } \
        PH_END

__global__ __launch_bounds__(512, 2) void gemm1_kernel(
    const unsigned short* __restrict__ A, const unsigned short* __restrict__ Bw,
    const float* __restrict__ bias, unsigned short* __restrict__ Cbf) {
    constexpr int K = 512;
    constexpr int NT = K / 64;
    constexpr int NXT = 8;                 // N = 2048
    constexpr int NC = 2048;

    extern __shared__ unsigned short lds[];
    unsigned short* A0lds = lds;
    unsigned short* B0lds = lds + 16384;
    unsigned short* A1lds = lds + 32768;
    unsigned short* B1lds = lds + 49152;

    const int nwg = (int)gridDim.x;
    const int orig = (int)blockIdx.x;
    const int q8 = nwg >> 3, r8 = nwg & 7;
    const int xcd = orig & 7, idx = orig >> 3;
    const int w = (xcd < r8 ? xcd * (q8 + 1) : r8 * (q8 + 1) + (xcd - r8) * q8) + idx;
    const int mt_i = w / NXT, nt_i = w % NXT;
    const size_t arow0 = (size_t)mt_i * 256;
    const int n0 = nt_i * 256;

    const int tid = threadIdx.x;
    const int l = tid & 63, wv = tid >> 6;
    const int wm = wv >> 2, wn = wv & 3;
    const int lr = l & 15, lq = l >> 4;

    const int srow = tid >> 3;
    const int skb = ((((tid & 7) << 4) ^ ((srow & 7) << 4)) >> 1);

    const int sw = (lr & 7) << 4;
    int kk2[2];
    kk2[0] = ((lq * 16) ^ sw) >> 1;
    kk2[1] = ((64 + lq * 16) ^ sw) >> 1;
    int aoffs[8], boffs[4];
#pragma unroll
    for (int mf = 0; mf < 8; ++mf) aoffs[mf] = (wm * 128 + mf * 16 + lr) * 64;
#pragma unroll
    for (int nf = 0; nf < 4; ++nf) boffs[nf] = (wn * 64 + nf * 16 + lr) * 64;

    f32x4 acc[8][4];
#pragma unroll
    for (int i = 0; i < 8; ++i)
#pragma unroll
        for (int j = 0; j < 4; ++j) acc[i][j] = (f32x4){0.f, 0.f, 0.f, 0.f};

    short8 bb00, bb01, bb10, bb11, bb20, bb21, bb30, bb31;

    const unsigned short* Ath = A + (arow0 + srow) * (size_t)K + skb;
    const unsigned short* Bth = Bw + ((size_t)n0 + srow) * K + skb;

    auto stageA = [&](int tile, unsigned short* dst, int half) {
        const unsigned short* g = Ath + (size_t)half * (128 * K) + tile * 64;
        unsigned short* d = dst + half * 8192 + tid * 8;
        GLOAD16(g, d);
        GLOAD16(g + (size_t)64 * K, d + 4096);
    };
    auto stageB = [&](int tile, unsigned short* dst, int half) {
        const unsigned short* g = Bth + (size_t)half * (128 * K) + tile * 64;
        unsigned short* d = dst + half * 8192 + tid * 8;
        GLOAD16(g, d);
        GLOAD16(g + (size_t)64 * K, d + 4096);
    };

    stageB(0, B0lds, 0);
    stageB(0, B0lds, 1);
    stageA(0, A0lds, 0);
    stageA(0, A0lds, 1);
    stageB(1, B1lds, 0);
    stageB(1, B1lds, 1);
    asm volatile("s_waitcnt vmcnt(4)" ::: "memory");
    __builtin_amdgcn_s_barrier();

#pragma unroll 1
    for (int t = 0; t < NT / 2 - 1; ++t) {
        const int v = 2 * t + 1, u2 = 2 * t + 2, v2 = 2 * t + 3;
        GEMM_BODY(1)
    }
    {
        const int t = NT / 2 - 1;
        const int v = 2 * t + 1, u2 = 2 * t + 2, v2 = 2 * t + 3;
        (void)u2; (void)v2;
        GEMM_BODY(0)
    }

    float bv[4];
#pragma unroll
    for (int nf = 0; nf < 4; ++nf) bv[nf] = bias[n0 + wn * 64 + nf * 16 + lr];

#pragma unroll
    for (int mf = 0; mf < 8; ++mf) {
#pragma unroll
        for (int qq = 0; qq < 4; ++qq) {
            long row = (long)arow0 + wm * 128 + mf * 16 + lq * 4 + qq;
#pragma unroll
            for (int nf = 0; nf < 4; ++nf) {
                int col = n0 + wn * 64 + nf * 16 + lr;
                float vvv = acc[mf][nf][qq] + bv[nf];
                Cbf[(size_t)row * NC + col] = f2bf(fmaxf(vvv, 0.f));
            }
        }
    }
}

// ---------- FFN2 + LN2 fused: y = LN(t1 @ W2^T + bW2 + h) ----------
// v2: 1024 threads, 16 waves (2m x 8n), wave tile 64x64, BK=32, LDS 80 KB.
// Simple 2-phase loop (stage-next -> read -> MFMA -> syncthreads); TLP = 4 waves/SIMD.
// Linear LDS (full-row frag reads are bandwidth-even; no swizzle needed).
__global__ __launch_bounds__(1024) void gemm2ln_kernel(
    const unsigned short* __restrict__ A,      // t1 chunk [rows][2048]
    const unsigned short* __restrict__ Bw,     // W2T [512][2048]
    const float* __restrict__ bias,            // bW2
    const unsigned short* __restrict__ hres,   // h bf16 (full, global rows)
    const float* __restrict__ g2, const float* __restrict__ b2,
    float* __restrict__ y, long out_row0) {
    constexpr int K = 2048;
    constexpr int NT = K / 32;                 // 64 K-tiles of BK=32

    extern __shared__ unsigned short lds[];
    // layout (ushort units): A0 [0,4096) A1 [4096,8192) B0 [8192,24576) B1 [24576,40960)

    const int nwg = (int)gridDim.x;
    const int orig = (int)blockIdx.x;
    const int q8 = nwg >> 3, r8 = nwg & 7;
    const int xcd = orig & 7, idx = orig >> 3;
    const int w = (xcd < r8 ? xcd * (q8 + 1) : r8 * (q8 + 1) + (xcd - r8) * q8) + idx;
    const size_t arow0 = (size_t)w * 128;

    const int tid = threadIdx.x;
    const int l = tid & 63, wv = tid >> 6;     // wv 0..15
    const int wm = wv >> 3, wn = wv & 7;       // 2 m-waves x 8 n-waves
    const int lr = l & 15, lq = l >> 4;

    int aoffs[4], boffs[4];
#pragma unroll
    for (int mf = 0; mf < 4; ++mf) aoffs[mf] = (wm * 64 + mf * 16 + lr) * 32 + lq * 8;
#pragma unroll
    for (int nf = 0; nf < 4; ++nf) boffs[nf] = (wn * 64 + nf * 16 + lr) * 32 + lq * 8;

    f32x4 acc[4][4];
#pragma unroll
    for (int i = 0; i < 4; ++i)
#pragma unroll
        for (int j = 0; j < 4; ++j) acc[i][j] = (f32x4){0.f, 0.f, 0.f, 0.f};

    // staging bases: thread covers 16 B at (row = tid>>2, granule = tid&3)
    const unsigned short* At = A + ((size_t)arow0 + (tid >> 2)) * K + (tid & 3) * 8;
    const unsigned short* Bt = Bw + (size_t)(tid >> 2) * K + (tid & 3) * 8;

    auto stage = [&](int t, int bi) {
        if (tid < 512)
            GLOAD16(At + t * 32, lds + bi * 4096 + tid * 8);            // A: 128x32 (waves 0-7)
        GLOAD16(Bt + t * 32, lds + 8192 + bi * 16384 + tid * 8);        // B rows 0-255
        GLOAD16(Bt + (size_t)256 * K + t * 32,
                lds + 8192 + bi * 16384 + 8192 + tid * 8);              // B rows 256-511
    };

    stage(0, 0);
    __syncthreads();

    int cur = 0;
#pragma unroll 1
    for (int t = 0; t < NT; ++t) {
        if (t + 1 < NT) stage(t + 1, cur ^ 1);
        const unsigned short* Ab = lds + cur * 4096;
        const unsigned short* Bb = lds + 8192 + cur * 16384;
        short8 af[4], bf4[4];
#pragma unroll
        for (int mf = 0; mf < 4; ++mf) af[mf] = *(const short8*)(Ab + aoffs[mf]);
#pragma unroll
        for (int nf = 0; nf < 4; ++nf) bf4[nf] = *(const short8*)(Bb + boffs[nf]);
#pragma unroll
        for (int mf = 0; mf < 4; ++mf)
#pragma unroll
            for (int nf = 0; nf < 4; ++nf)
                acc[mf][nf] = mfma16(af[mf], bf4[nf], acc[mf][nf]);
        __syncthreads();
        cur ^= 1;
    }

    // ---- epilogue: bias + bf16-h residual, row LN across block, write y ----
    float* red = (float*)lds;                  // [8 chunks][128] sum, then +1024 sq
    float bv2[4], gv2[4], bb2[4];
#pragma unroll
    for (int nf = 0; nf < 4; ++nf) {
        int col = wn * 64 + nf * 16 + lr;
        bv2[nf] = bias[col];
        gv2[nf] = g2[col];
        bb2[nf] = b2[col];
    }

#pragma unroll
    for (int mf = 0; mf < 4; ++mf) {
#pragma unroll
        for (int qq = 0; qq < 4; ++qq) {
            int lrow = wm * 64 + mf * 16 + lq * 4 + qq;
            long grow = out_row0 + (long)arow0 + lrow;
            const unsigned short* hr = hres + (size_t)grow * 512 + wn * 64 + lr;
            float s = 0.f, s2 = 0.f;
#pragma unroll
            for (int nf = 0; nf < 4; ++nf) {
                float z = acc[mf][nf][qq] + bv2[nf] + bf2f(hr[nf * 16]);
                acc[mf][nf][qq] = z;
                s += z;
                s2 += z * z;
            }
            s += __shfl_xor(s, 1, 16); s2 += __shfl_xor(s2, 1, 16);
            s += __shfl_xor(s, 2, 16); s2 += __shfl_xor(s2, 2, 16);
            s += __shfl_xor(s, 4, 16); s2 += __shfl_xor(s2, 4, 16);
            s += __shfl_xor(s, 8, 16); s2 += __shfl_xor(s2, 8, 16);
            if (lr == 0) {
                red[wn * 128 + lrow] = s;
                red[1024 + wn * 128 + lrow] = s2;
            }
        }
    }
    __syncthreads();

#pragma unroll
    for (int mf = 0; mf < 4; ++mf) {
#pragma unroll
        for (int qq = 0; qq < 4; ++qq) {
            int lrow = wm * 64 + mf * 16 + lq * 4 + qq;
            long grow = out_row0 + (long)arow0 + lrow;
            float s = 0.f, s2 = 0.f;
#pragma unroll
            for (int cc = 0; cc < 8; ++cc) {
                s += red[cc * 128 + lrow];
                s2 += red[1024 + cc * 128 + lrow];
            }
            float mu = s * (1.f / 512.f);
            float var = s2 * (1.f / 512.f) - mu * mu;
            float inv = rsqrtf(var + 1e-5f);
            float* yr = y + (size_t)grow * 512 + wn * 64 + lr;
#pragma unroll
            for (int nf = 0; nf < 4; ++nf)
                yr[nf * 16] = (acc[mf][nf][qq] - mu) * inv * gv2[nf] + bb2[nf];
        }
    }
}

// ---------- host ----------
extern "C" void kernel_launch(void* const* d_in, const int* in_sizes, int n_in,
                              void* d_out, int out_size, void* d_ws, size_t ws_size,
                              hipStream_t stream) {
    const float* x = (const float*)d_in[0];
    const void* mask = d_in[1];
    const float* g1 = (const float*)d_in[2];
    const float* b1 = (const float*)d_in[3];
    const float* g2 = (const float*)d_in[4];
    const float* b2 = (const float*)d_in[5];
    const float* W1 = (const float*)d_in[6];
    const float* bW1 = (const float*)d_in[7];
    const float* W2 = (const float*)d_in[8];
    const float* bW2 = (const float*)d_in[9];

    float* y = (float*)d_out;
    float* attn = y + Y_ELEMS;
    char* ws = (char*)d_ws;
    unsigned short* W1T = (unsigned short*)(ws);                 // 2 MiB  [2048][512]
    unsigned short* W2T = (unsigned short*)(ws + 2097152);       // 2 MiB  [512][2048]
    int* flag = (int*)(ws + 4194304);
    unsigned short* h = (unsigned short*)(ws + 4194560);         // 64 MiB [65536][512] bf16
    unsigned short* t1 = (unsigned short*)(ws + 71303424ULL);    // [chunk*256][2048] bf16

    hipFuncSetAttribute((const void*)gemm1_kernel,
                        hipFuncAttributeMaxDynamicSharedMemorySize, 131072);
    hipFuncSetAttribute((const void*)gemm2ln_kernel,
                        hipFuncAttributeMaxDynamicSharedMemorySize, 81920);

    long cap256 = ((long)ws_size - 71303424L) / (256L * 2048L * 2L);
    if (cap256 < 1) cap256 = 1;
    if (cap256 > 256) cap256 = 256;

    transpose_kernel<<<dim3(64, 16), dim3(256), 0, stream>>>(W1, W1T, 512, 2048);
    transpose_kernel<<<dim3(16, 64), dim3(256), 0, stream>>>(W2, W2T, 2048, 512);
    detect_kernel<<<1, 256, 0, stream>>>((const unsigned char*)mask, flag);
    stage1_kernel<<<4096, 256, 0, stream>>>(x, (const unsigned char*)mask, (const int*)mask,
                                            flag, g1, b1, attn, h);
    for (long t0 = 0; t0 < 256; t0 += cap256) {
        long mt = (256 - t0 < cap256) ? (256 - t0) : cap256;
        long row0 = t0 * 256;
        gemm1_kernel<<<dim3((unsigned)(8 * mt)), 512, 131072, stream>>>(
            h + (size_t)row0 * 512, W1T, bW1, t1);
        gemm2ln_kernel<<<dim3((unsigned)(2 * mt)), 1024, 81920, stream>>>(
            t1, W2T, bW2, h, g2, b2, y, row0);
    }
}

// Round 10
// 464.209 us; speedup vs baseline: 1.0008x; 1.0008x over previous
//
#include <hip/hip_runtime.h>

// ---------- types & helpers ----------
typedef float  f32x4 __attribute__((ext_vector_type(4)));
typedef short  short8 __attribute__((ext_vector_type(8)));

__device__ __forceinline__ unsigned short f2bf(float f) {
    unsigned u = __builtin_bit_cast(unsigned, f);
    unsigned r = u + 0x7FFFu + ((u >> 16) & 1u);
    return (unsigned short)(r >> 16);
}
__device__ __forceinline__ float bf2f(unsigned short b) {
    return __builtin_bit_cast(float, (unsigned)b << 16);
}

__device__ __forceinline__ f32x4 mfma16(short8 a, short8 b, f32x4 c) {
    return __builtin_amdgcn_mfma_f32_16x16x32_bf16(a, b, c, 0, 0, 0);
}

#define GLOAD16(gp, lp) \
    __builtin_amdgcn_global_load_lds((const __attribute__((address_space(1))) unsigned int*)(gp), \
                                     (__attribute__((address_space(3))) unsigned int*)(lp), 16, 0, 0)

// ---------- constants ----------
#define BT   4096
#define NTOK 16
#define DDIM 512
#define Y_ELEMS 33554432ULL        // BT*NTOK*DDIM
#define XS_STRIDE 516

// ---------- weight transpose fp32 [R][C] -> bf16 [C][R] ----------
__global__ __launch_bounds__(256) void transpose_kernel(const float* __restrict__ in,
                                                        unsigned short* __restrict__ out,
                                                        int R, int C) {
    __shared__ float tile[32][33];
    const int tx = threadIdx.x & 31, ty = threadIdx.x >> 5;
    const int c0 = blockIdx.x * 32, r0 = blockIdx.y * 32;
#pragma unroll
    for (int i = 0; i < 4; ++i)
        tile[ty + 8 * i][tx] = in[(size_t)(r0 + ty + 8 * i) * C + c0 + tx];
    __syncthreads();
#pragma unroll
    for (int i = 0; i < 4; ++i)
        out[(size_t)(c0 + ty + 8 * i) * R + r0 + tx] = f2bf(tile[tx][ty + 8 * i]);
}

// ---------- mask dtype detection ----------
__global__ void detect_kernel(const unsigned char* __restrict__ m, int* __restrict__ flag) {
    __shared__ int any;
    if (threadIdx.x == 0) any = 0;
    __syncthreads();
    int loc = 0;
    for (int i = threadIdx.x; i < 4096; i += 256)
        if (i & 3) loc |= m[i];
    if (loc) atomicOr(&any, 1);
    __syncthreads();
    if (threadIdx.x == 0) *flag = any ? 1 : 0;
}

// ---------- stage 1 (pure fp32): scores, softmax, p@x, LN1 -> h (bf16 only) ----------
__global__ __launch_bounds__(256) void stage1_kernel(
    const float* __restrict__ x,
    const unsigned char* __restrict__ mask_u8, const int* __restrict__ mask_i32,
    const int* __restrict__ flagp,
    const float* __restrict__ g1, const float* __restrict__ b1,
    float* __restrict__ attn_out, unsigned short* __restrict__ hbf) {
    __shared__ float xs[NTOK * XS_STRIDE];
    __shared__ float p_lds[256];

    const int b = blockIdx.x, t = threadIdx.x;
    const float* xb = x + (size_t)b * (NTOK * DDIM);

#pragma unroll
    for (int i = 0; i < 8; ++i) {
        int s = t + 256 * i;
        int r = s >> 7, c4 = s & 127;
        f32x4 v = ((const f32x4*)xb)[s];
        *(f32x4*)(&xs[r * XS_STRIDE + c4 * 4]) = v;
    }
    __syncthreads();

    const int r = t >> 4, c = t & 15;
    {
        const f32x4* xr = (const f32x4*)(&xs[r * XS_STRIDE]);
        const f32x4* xc = (const f32x4*)(&xs[c * XS_STRIDE]);
        f32x4 d4 = {0.f, 0.f, 0.f, 0.f};
#pragma unroll 8
        for (int u = 0; u < 128; ++u) d4 += xr[u] * xc[u];
        float s_rc = (d4.x + d4.y + d4.z + d4.w) * 0.04419417382415922f;

        const int flag = *flagp;
        size_t midx = (size_t)b * 256 + t;
        bool msk = flag ? (mask_u8[midx] != 0) : (mask_i32[midx] != 0);
        float sv = msk ? -1e30f : s_rc;
        float mx = sv;
        mx = fmaxf(mx, __shfl_xor(mx, 1, 16));
        mx = fmaxf(mx, __shfl_xor(mx, 2, 16));
        mx = fmaxf(mx, __shfl_xor(mx, 4, 16));
        mx = fmaxf(mx, __shfl_xor(mx, 8, 16));
        float e = msk ? 0.f : expf(sv - mx);
        float sum = e;
        sum += __shfl_xor(sum, 1, 16);
        sum += __shfl_xor(sum, 2, 16);
        sum += __shfl_xor(sum, 4, 16);
        sum += __shfl_xor(sum, 8, 16);
        float p = e / sum;
        p_lds[t] = p;
        attn_out[midx] = p;
    }
    __syncthreads();

    const int r2 = t >> 4, tc = t & 15;
    f32x4 acc[8];
#pragma unroll
    for (int j = 0; j < 8; ++j) acc[j] = (f32x4){0.f, 0.f, 0.f, 0.f};
    for (int c2 = 0; c2 < 16; ++c2) {
        float pw = p_lds[r2 * 16 + c2];
        const f32x4* xrow = (const f32x4*)(&xs[c2 * XS_STRIDE]);
#pragma unroll
        for (int j = 0; j < 8; ++j) acc[j] += pw * xrow[tc + 16 * j];
    }

    const f32x4* xme = (const f32x4*)(&xs[r2 * XS_STRIDE]);
    f32x4 vv[8];
    float s1 = 0.f, s2 = 0.f;
#pragma unroll
    for (int j = 0; j < 8; ++j) {
        f32x4 v = xme[tc + 16 * j] + acc[j];
        vv[j] = v;
        s1 += v.x + v.y + v.z + v.w;
        s2 += v.x * v.x + v.y * v.y + v.z * v.z + v.w * v.w;
    }
    s1 += __shfl_xor(s1, 1, 16); s2 += __shfl_xor(s2, 1, 16);
    s1 += __shfl_xor(s1, 2, 16); s2 += __shfl_xor(s2, 2, 16);
    s1 += __shfl_xor(s1, 4, 16); s2 += __shfl_xor(s2, 4, 16);
    s1 += __shfl_xor(s1, 8, 16); s2 += __shfl_xor(s2, 8, 16);
    float mu = s1 * (1.f / 512.f);
    float var = s2 * (1.f / 512.f) - mu * mu;
    float inv = rsqrtf(var + 1e-5f);

    unsigned short* hrow = hbf + (size_t)(b * NTOK + r2) * DDIM;
#pragma unroll
    for (int j = 0; j < 8; ++j) {
        int u = tc + 16 * j;
        f32x4 gv = ((const f32x4*)g1)[u];
        f32x4 bv = ((const f32x4*)b1)[u];
        f32x4 o = (vv[j] - mu) * inv * gv + bv;
        uint2 pk;
        pk.x = (unsigned)f2bf(o.x) | ((unsigned)f2bf(o.y) << 16);
        pk.y = (unsigned)f2bf(o.z) | ((unsigned)f2bf(o.w) << 16);
        *(uint2*)(hrow + u * 4) = pk;
    }
}

// ---------- FFN1: 8-phase 256x256 GEMM, one barrier per phase (round-8 proven) ----------
#define PH_READA(Al, Q) { short8 a00, a01, a10, a11; \
    a00 = *(const short8*)((Al) + aoffs[2*(Q)]   + kk2[0]); \
    a01 = *(const short8*)((Al) + aoffs[2*(Q)]   + kk2[1]); \
    a10 = *(const short8*)((Al) + aoffs[2*(Q)+1] + kk2[0]); \
    a11 = *(const short8*)((Al) + aoffs[2*(Q)+1] + kk2[1]);

#define PH_READB(Bl) \
    bb00 = *(const short8*)((Bl) + boffs[0] + kk2[0]); \
    bb01 = *(const short8*)((Bl) + boffs[0] + kk2[1]); \
    bb10 = *(const short8*)((Bl) + boffs[1] + kk2[0]); \
    bb11 = *(const short8*)((Bl) + boffs[1] + kk2[1]); \
    bb20 = *(const short8*)((Bl) + boffs[2] + kk2[0]); \
    bb21 = *(const short8*)((Bl) + boffs[2] + kk2[1]); \
    bb30 = *(const short8*)((Bl) + boffs[3] + kk2[0]); \
    bb31 = *(const short8*)((Bl) + boffs[3] + kk2[1]);

#define PH_MFMA(Q) \
    asm volatile("s_waitcnt lgkmcnt(0)" ::: "memory"); \
    __builtin_amdgcn_sched_barrier(0); \
    __builtin_amdgcn_s_setprio(1); \
    acc[2*(Q)][0]   = mfma16(a00, bb00, acc[2*(Q)][0]); \
    acc[2*(Q)][0]   = mfma16(a01, bb01, acc[2*(Q)][0]); \
    acc[2*(Q)][1]   = mfma16(a00, bb10, acc[2*(Q)][1]); \
    acc[2*(Q)][1]   = mfma16(a01, bb11, acc[2*(Q)][1]); \
    acc[2*(Q)][2]   = mfma16(a00, bb20, acc[2*(Q)][2]); \
    acc[2*(Q)][2]   = mfma16(a01, bb21, acc[2*(Q)][2]); \
    acc[2*(Q)][3]   = mfma16(a00, bb30, acc[2*(Q)][3]); \
    acc[2*(Q)][3]   = mfma16(a01, bb31, acc[2*(Q)][3]); \
    acc[2*(Q)+1][0] = mfma16(a10, bb00, acc[2*(Q)+1][0]); \
    acc[2*(Q)+1][0] = mfma16(a11, bb01, acc[2*(Q)+1][0]); \
    acc[2*(Q)+1][1] = mfma16(a10, bb10, acc[2*(Q)+1][1]); \
    acc[2*(Q)+1][1] = mfma16(a11, bb11, acc[2*(Q)+1][1]); \
    acc[2*(Q)+1][2] = mfma16(a10, bb20, acc[2*(Q)+1][2]); \
    acc[2*(Q)+1][2] = mfma16(a11, bb21, acc[2*(Q)+1][2]); \
    acc[2*(Q)+1][3] = mfma16(a10, bb30, acc[2*(Q)+1][3]); \
    acc[2*(Q)+1][3] = mfma16(a11, bb31, acc[2*(Q)+1][3]); \
    __builtin_amdgcn_s_setprio(0);

#define PH_END  __builtin_amdgcn_s_barrier(); }

#define GEMM_BODY(MORE) \
        PH_READA(A0lds, 0) PH_READB(B0lds) \
        stageA(v, A1lds, 0); stageA(v, A1lds, 1); \
        PH_MFMA(0) PH_END \
        PH_READA(A0lds, 1) \
        if (MORE) stageB(u2, B0lds, 0); \
        PH_MFMA(1) PH_END \
        PH_READA(A0lds, 2) \
        if (MORE) stageB(u2, B0lds, 1); \
        PH_MFMA(2) PH_END \
        PH_READA(A0lds, 3) \
        PH_MFMA(3) \
        if (MORE) { asm volatile("s_waitcnt vmcnt(4)" ::: "memory"); } \
        else      { asm volatile("s_waitcnt vmcnt(0)" ::: "memory"); } \
        PH_END \
        PH_READA(A1lds, 0) PH_READB(B1lds) \
        if (MORE) stageA(u2, A0lds, 0); \
        PH_MFMA(0) PH_END \
        PH_READA(A1lds, 1) \
        if (MORE) stageA(u2, A0lds, 1); \
        PH_MFMA(1) PH_END \
        PH_READA(A1lds, 2) \
        if (MORE) stageB(v2, B1lds, 0); \
        PH_MFMA(2) PH_END \
        PH_READA(A1lds, 3) \
        if (MORE) stageB(v2, B1lds, 1); \
        PH_MFMA(3) \
        if (MORE) { asm volatile("s_waitcnt vmcnt(4)" ::: "memory"); } \
        PH_END

__global__ __launch_bounds__(512, 2) void gemm1_kernel(
    const unsigned short* __restrict__ A, const unsigned short* __restrict__ Bw,
    const float* __restrict__ bias, unsigned short* __restrict__ Cbf) {
    constexpr int K = 512;
    constexpr int NT = K / 64;
    constexpr int NXT = 8;                 // N = 2048
    constexpr int NC = 2048;

    extern __shared__ unsigned short lds[];
    unsigned short* A0lds = lds;
    unsigned short* B0lds = lds + 16384;
    unsigned short* A1lds = lds + 32768;
    unsigned short* B1lds = lds + 49152;

    const int nwg = (int)gridDim.x;
    const int orig = (int)blockIdx.x;
    const int q8 = nwg >> 3, r8 = nwg & 7;
    const int xcd = orig & 7, idx = orig >> 3;
    const int w = (xcd < r8 ? xcd * (q8 + 1) : r8 * (q8 + 1) + (xcd - r8) * q8) + idx;
    const int mt_i = w / NXT, nt_i = w % NXT;
    const size_t arow0 = (size_t)mt_i * 256;
    const int n0 = nt_i * 256;

    const int tid = threadIdx.x;
    const int l = tid & 63, wv = tid >> 6;
    const int wm = wv >> 2, wn = wv & 3;
    const int lr = l & 15, lq = l >> 4;

    const int srow = tid >> 3;
    const int skb = ((((tid & 7) << 4) ^ ((srow & 7) << 4)) >> 1);

    const int sw = (lr & 7) << 4;
    int kk2[2];
    kk2[0] = ((lq * 16) ^ sw) >> 1;
    kk2[1] = ((64 + lq * 16) ^ sw) >> 1;
    int aoffs[8], boffs[4];
#pragma unroll
    for (int mf = 0; mf < 8; ++mf) aoffs[mf] = (wm * 128 + mf * 16 + lr) * 64;
#pragma unroll
    for (int nf = 0; nf < 4; ++nf) boffs[nf] = (wn * 64 + nf * 16 + lr) * 64;

    f32x4 acc[8][4];
#pragma unroll
    for (int i = 0; i < 8; ++i)
#pragma unroll
        for (int j = 0; j < 4; ++j) acc[i][j] = (f32x4){0.f, 0.f, 0.f, 0.f};

    short8 bb00, bb01, bb10, bb11, bb20, bb21, bb30, bb31;

    const unsigned short* Ath = A + (arow0 + srow) * (size_t)K + skb;
    const unsigned short* Bth = Bw + ((size_t)n0 + srow) * K + skb;

    auto stageA = [&](int tile, unsigned short* dst, int half) {
        const unsigned short* g = Ath + (size_t)half * (128 * K) + tile * 64;
        unsigned short* d = dst + half * 8192 + tid * 8;
        GLOAD16(g, d);
        GLOAD16(g + (size_t)64 * K, d + 4096);
    };
    auto stageB = [&](int tile, unsigned short* dst, int half) {
        const unsigned short* g = Bth + (size_t)half * (128 * K) + tile * 64;
        unsigned short* d = dst + half * 8192 + tid * 8;
        GLOAD16(g, d);
        GLOAD16(g + (size_t)64 * K, d + 4096);
    };

    stageB(0, B0lds, 0);
    stageB(0, B0lds, 1);
    stageA(0, A0lds, 0);
    stageA(0, A0lds, 1);
    stageB(1, B1lds, 0);
    stageB(1, B1lds, 1);
    asm volatile("s_waitcnt vmcnt(4)" ::: "memory");
    __builtin_amdgcn_s_barrier();

#pragma unroll 1
    for (int t = 0; t < NT / 2 - 1; ++t) {
        const int v = 2 * t + 1, u2 = 2 * t + 2, v2 = 2 * t + 3;
        GEMM_BODY(1)
    }
    {
        const int t = NT / 2 - 1;
        const int v = 2 * t + 1, u2 = 2 * t + 2, v2 = 2 * t + 3;
        (void)u2; (void)v2;
        GEMM_BODY(0)
    }

    float bv[4];
#pragma unroll
    for (int nf = 0; nf < 4; ++nf) bv[nf] = bias[n0 + wn * 64 + nf * 16 + lr];

#pragma unroll
    for (int mf = 0; mf < 8; ++mf) {
#pragma unroll
        for (int qq = 0; qq < 4; ++qq) {
            long row = (long)arow0 + wm * 128 + mf * 16 + lq * 4 + qq;
#pragma unroll
            for (int nf = 0; nf < 4; ++nf) {
                int col = n0 + wn * 64 + nf * 16 + lr;
                float vvv = acc[mf][nf][qq] + bv[nf];
                Cbf[(size_t)row * NC + col] = f2bf(fmaxf(vvv, 0.f));
            }
        }
    }
}

// ---------- FFN2 + LN2 fused: y = LN(t1 @ W2^T + bW2 + h) ----------
// v3: 1024 threads, 16 waves (2m x 8n), wave tile 64x64, BK=32, LDS 80 KB,
// simple 2-phase loop + CONFLICT-FREE slot swizzle (round-9 fix):
//   LDS rows are 64 B = 4 slots of 16 B; element k-chunk c of row r lives at
//   slot c ^ ((r>>1)&3).  Read: lane (lr,lq) reads slot lq ^ ((row>>1)&3)
//   -> each lq-group tiles every bank-quad exactly 2x (2-way = free, m136).
//   Staging keeps LDS dest lane-linear; global SOURCE granule is pre-swizzled
//   g = (tid&3) ^ ((tid>>3)&3)  (both-sides-or-neither rule).
__global__ __launch_bounds__(1024) void gemm2ln_kernel(
    const unsigned short* __restrict__ A,      // t1 chunk [rows][2048]
    const unsigned short* __restrict__ Bw,     // W2T [512][2048]
    const float* __restrict__ bias,            // bW2
    const unsigned short* __restrict__ hres,   // h bf16 (full, global rows)
    const float* __restrict__ g2, const float* __restrict__ b2,
    float* __restrict__ y, long out_row0) {
    constexpr int K = 2048;
    constexpr int NT = K / 32;                 // 64 K-tiles of BK=32

    extern __shared__ unsigned short lds[];
    // layout (ushort units): A0 [0,4096) A1 [4096,8192) B0 [8192,24576) B1 [24576,40960)

    const int nwg = (int)gridDim.x;
    const int orig = (int)blockIdx.x;
    const int q8 = nwg >> 3, r8 = nwg & 7;
    const int xcd = orig & 7, idx = orig >> 3;
    const int w = (xcd < r8 ? xcd * (q8 + 1) : r8 * (q8 + 1) + (xcd - r8) * q8) + idx;
    const size_t arow0 = (size_t)w * 128;

    const int tid = threadIdx.x;
    const int l = tid & 63, wv = tid >> 6;     // wv 0..15
    const int wm = wv >> 3, wn = wv & 7;       // 2 m-waves x 8 n-waves
    const int lr = l & 15, lq = l >> 4;

    int aoffs[4], boffs[4];
#pragma unroll
    for (int mf = 0; mf < 4; ++mf) {
        int row = wm * 64 + mf * 16 + lr;
        aoffs[mf] = row * 32 + ((lq ^ ((row >> 1) & 3)) * 8);
    }
#pragma unroll
    for (int nf = 0; nf < 4; ++nf) {
        int row = wn * 64 + nf * 16 + lr;
        boffs[nf] = row * 32 + ((lq ^ ((row >> 1) & 3)) * 8);
    }

    f32x4 acc[4][4];
#pragma unroll
    for (int i = 0; i < 4; ++i)
#pragma unroll
        for (int j = 0; j < 4; ++j) acc[i][j] = (f32x4){0.f, 0.f, 0.f, 0.f};

    // staging: thread covers LDS row = tid>>2, slot = tid&3 (lane-linear dest);
    // fetch the k-chunk that the swizzled read expects there:
    const int gsw = (tid & 3) ^ ((tid >> 3) & 3);
    const unsigned short* At = A + ((size_t)arow0 + (tid >> 2)) * K + gsw * 8;
    const unsigned short* Bt = Bw + (size_t)(tid >> 2) * K + gsw * 8;

    auto stage = [&](int t, int bi) {
        if (tid < 512)
            GLOAD16(At + t * 32, lds + bi * 4096 + tid * 8);            // A: 128x32 (waves 0-7)
        GLOAD16(Bt + t * 32, lds + 8192 + bi * 16384 + tid * 8);        // B rows 0-255
        GLOAD16(Bt + (size_t)256 * K + t * 32,
                lds + 8192 + bi * 16384 + 8192 + tid * 8);              // B rows 256-511
    };

    stage(0, 0);
    __syncthreads();

    int cur = 0;
#pragma unroll 1
    for (int t = 0; t < NT; ++t) {
        if (t + 1 < NT) stage(t + 1, cur ^ 1);
        const unsigned short* Ab = lds + cur * 4096;
        const unsigned short* Bb = lds + 8192 + cur * 16384;
        short8 af[4], bf4[4];
#pragma unroll
        for (int mf = 0; mf < 4; ++mf) af[mf] = *(const short8*)(Ab + aoffs[mf]);
#pragma unroll
        for (int nf = 0; nf < 4; ++nf) bf4[nf] = *(const short8*)(Bb + boffs[nf]);
#pragma unroll
        for (int mf = 0; mf < 4; ++mf)
#pragma unroll
            for (int nf = 0; nf < 4; ++nf)
                acc[mf][nf] = mfma16(af[mf], bf4[nf], acc[mf][nf]);
        __syncthreads();
        cur ^= 1;
    }

    // ---- epilogue: bias + bf16-h residual, row LN across block, write y ----
    float* red = (float*)lds;                  // [8 chunks][128] sum, then +1024 sq
    float bv2[4], gv2[4], bb2[4];
#pragma unroll
    for (int nf = 0; nf < 4; ++nf) {
        int col = wn * 64 + nf * 16 + lr;
        bv2[nf] = bias[col];
        gv2[nf] = g2[col];
        bb2[nf] = b2[col];
    }

#pragma unroll
    for (int mf = 0; mf < 4; ++mf) {
#pragma unroll
        for (int qq = 0; qq < 4; ++qq) {
            int lrow = wm * 64 + mf * 16 + lq * 4 + qq;
            long grow = out_row0 + (long)arow0 + lrow;
            const unsigned short* hr = hres + (size_t)grow * 512 + wn * 64 + lr;
            float s = 0.f, s2 = 0.f;
#pragma unroll
            for (int nf = 0; nf < 4; ++nf) {
                float z = acc[mf][nf][qq] + bv2[nf] + bf2f(hr[nf * 16]);
                acc[mf][nf][qq] = z;
                s += z;
                s2 += z * z;
            }
            s += __shfl_xor(s, 1, 16); s2 += __shfl_xor(s2, 1, 16);
            s += __shfl_xor(s, 2, 16); s2 += __shfl_xor(s2, 2, 16);
            s += __shfl_xor(s, 4, 16); s2 += __shfl_xor(s2, 4, 16);
            s += __shfl_xor(s, 8, 16); s2 += __shfl_xor(s2, 8, 16);
            if (lr == 0) {
                red[wn * 128 + lrow] = s;
                red[1024 + wn * 128 + lrow] = s2;
            }
        }
    }
    __syncthreads();

#pragma unroll
    for (int mf = 0; mf < 4; ++mf) {
#pragma unroll
        for (int qq = 0; qq < 4; ++qq) {
            int lrow = wm * 64 + mf * 16 + lq * 4 + qq;
            long grow = out_row0 + (long)arow0 + lrow;
            float s = 0.f, s2 = 0.f;
#pragma unroll
            for (int cc = 0; cc < 8; ++cc) {
                s += red[cc * 128 + lrow];
                s2 += red[1024 + cc * 128 + lrow];
            }
            float mu = s * (1.f / 512.f);
            float var = s2 * (1.f / 512.f) - mu * mu;
            float inv = rsqrtf(var + 1e-5f);
            float* yr = y + (size_t)grow * 512 + wn * 64 + lr;
#pragma unroll
            for (int nf = 0; nf < 4; ++nf)
                yr[nf * 16] = (acc[mf][nf][qq] - mu) * inv * gv2[nf] + bb2[nf];
        }
    }
}

// ---------- host ----------
extern "C" void kernel_launch(void* const* d_in, const int* in_sizes, int n_in,
                              void* d_out, int out_size, void* d_ws, size_t ws_size,
                              hipStream_t stream) {
    const float* x = (const float*)d_in[0];
    const void* mask = d_in[1];
    const float* g1 = (const float*)d_in[2];
    const float* b1 = (const float*)d_in[3];
    const float* g2 = (const float*)d_in[4];
    const float* b2 = (const float*)d_in[5];
    const float* W1 = (const float*)d_in[6];
    const float* bW1 = (const float*)d_in[7];
    const float* W2 = (const float*)d_in[8];
    const float* bW2 = (const float*)d_in[9];

    float* y = (float*)d_out;
    float* attn = y + Y_ELEMS;
    char* ws = (char*)d_ws;
    unsigned short* W1T = (unsigned short*)(ws);                 // 2 MiB  [2048][512]
    unsigned short* W2T = (unsigned short*)(ws + 2097152);       // 2 MiB  [512][2048]
    int* flag = (int*)(ws + 4194304);
    unsigned short* h = (unsigned short*)(ws + 4194560);         // 64 MiB [65536][512] bf16
    unsigned short* t1 = (unsigned short*)(ws + 71303424ULL);    // [chunk*256][2048] bf16

    hipFuncSetAttribute((const void*)gemm1_kernel,
                        hipFuncAttributeMaxDynamicSharedMemorySize, 131072);
    hipFuncSetAttribute((const void*)gemm2ln_kernel,
                        hipFuncAttributeMaxDynamicSharedMemorySize, 81920);

    long cap256 = ((long)ws_size - 71303424L) / (256L * 2048L * 2L);
    if (cap256 < 1) cap256 = 1;
    if (cap256 > 256) cap256 = 256;

    transpose_kernel<<<dim3(64, 16), dim3(256), 0, stream>>>(W1, W1T, 512, 2048);
    transpose_kernel<<<dim3(16, 64), dim3(256), 0, stream>>>(W2, W2T, 2048, 512);
    detect_kernel<<<1, 256, 0, stream>>>((const unsigned char*)mask, flag);
    stage1_kernel<<<4096, 256, 0, stream>>>(x, (const unsigned char*)mask, (const int*)mask,
                                            flag, g1, b1, attn, h);
    for (long t0 = 0; t0 < 256; t0 += cap256) {
        long mt = (256 - t0 < cap256) ? (256 - t0) : cap256;
        long row0 = t0 * 256;
        gemm1_kernel<<<dim3((unsigned)(8 * mt)), 512, 131072, stream>>>(
            h + (size_t)row0 * 512, W1T, bW1, t1);
        gemm2ln_kernel<<<dim3((unsigned)(2 * mt)), 1024, 81920, stream>>>(
            t1, W2T, bW2, h, g2, b2, y, row0);
    }
}

// Round 11
// 393.357 us; speedup vs baseline: 1.1811x; 1.1801x over previous
//
#include <hip/hip_runtime.h>

// ---------- types & helpers ----------
typedef float  f32x4 __attribute__((ext_vector_type(4)));
typedef short  short8 __attribute__((ext_vector_type(8)));

__device__ __forceinline__ unsigned short f2bf(float f) {
    unsigned u = __builtin_bit_cast(unsigned, f);
    unsigned r = u + 0x7FFFu + ((u >> 16) & 1u);
    return (unsigned short)(r >> 16);
}
__device__ __forceinline__ float bf2f(unsigned short b) {
    return __builtin_bit_cast(float, (unsigned)b << 16);
}

__device__ __forceinline__ f32x4 mfma16(short8 a, short8 b, f32x4 c) {
    return __builtin_amdgcn_mfma_f32_16x16x32_bf16(a, b, c, 0, 0, 0);
}

#define GLOAD16(gp, lp) \
    __builtin_amdgcn_global_load_lds((const __attribute__((address_space(1))) unsigned int*)(gp), \
                                     (__attribute__((address_space(3))) unsigned int*)(lp), 16, 0, 0)

// ---------- constants ----------
#define BT   4096
#define NTOK 16
#define DDIM 512
#define Y_ELEMS 33554432ULL        // BT*NTOK*DDIM
#define XS_STRIDE 516

// ---------- weight transpose fp32 [R][C] -> bf16 [C][R], optional k-perm ----------
// perm=1: within each 64-wide k-group, k' = (k&15)*4 + ((k>>4)&3)  — matches
// gemm1's permuted t1 store so GEMM2 pairs t1[r][k] with W2T[n][k] consistently.
__global__ __launch_bounds__(256) void transpose_kernel(const float* __restrict__ in,
                                                        unsigned short* __restrict__ out,
                                                        int R, int C, int perm) {
    __shared__ float tile[32][33];
    const int tx = threadIdx.x & 31, ty = threadIdx.x >> 5;
    const int c0 = blockIdx.x * 32, r0 = blockIdx.y * 32;
#pragma unroll
    for (int i = 0; i < 4; ++i)
        tile[ty + 8 * i][tx] = in[(size_t)(r0 + ty + 8 * i) * C + c0 + tx];
    __syncthreads();
    const int k = r0 + tx;
    const int kp = perm ? ((k & ~63) | ((k & 15) << 2) | ((k >> 4) & 3)) : k;
#pragma unroll
    for (int i = 0; i < 4; ++i)
        out[(size_t)(c0 + ty + 8 * i) * R + kp] = f2bf(tile[tx][ty + 8 * i]);
}

// ---------- mask dtype detection ----------
__global__ void detect_kernel(const unsigned char* __restrict__ m, int* __restrict__ flag) {
    __shared__ int any;
    if (threadIdx.x == 0) any = 0;
    __syncthreads();
    int loc = 0;
    for (int i = threadIdx.x; i < 4096; i += 256)
        if (i & 3) loc |= m[i];
    if (loc) atomicOr(&any, 1);
    __syncthreads();
    if (threadIdx.x == 0) *flag = any ? 1 : 0;
}

// ---------- stage 1 (pure fp32): scores, softmax, p@x, LN1 -> h (bf16 only) ----------
__global__ __launch_bounds__(256) void stage1_kernel(
    const float* __restrict__ x,
    const unsigned char* __restrict__ mask_u8, const int* __restrict__ mask_i32,
    const int* __restrict__ flagp,
    const float* __restrict__ g1, const float* __restrict__ b1,
    float* __restrict__ attn_out, unsigned short* __restrict__ hbf) {
    __shared__ float xs[NTOK * XS_STRIDE];
    __shared__ float p_lds[256];

    const int b = blockIdx.x, t = threadIdx.x;
    const float* xb = x + (size_t)b * (NTOK * DDIM);

#pragma unroll
    for (int i = 0; i < 8; ++i) {
        int s = t + 256 * i;
        int r = s >> 7, c4 = s & 127;
        f32x4 v = ((const f32x4*)xb)[s];
        *(f32x4*)(&xs[r * XS_STRIDE + c4 * 4]) = v;
    }
    __syncthreads();

    const int r = t >> 4, c = t & 15;
    {
        const f32x4* xr = (const f32x4*)(&xs[r * XS_STRIDE]);
        const f32x4* xc = (const f32x4*)(&xs[c * XS_STRIDE]);
        f32x4 d4 = {0.f, 0.f, 0.f, 0.f};
#pragma unroll 8
        for (int u = 0; u < 128; ++u) d4 += xr[u] * xc[u];
        float s_rc = (d4.x + d4.y + d4.z + d4.w) * 0.04419417382415922f;

        const int flag = *flagp;
        size_t midx = (size_t)b * 256 + t;
        bool msk = flag ? (mask_u8[midx] != 0) : (mask_i32[midx] != 0);
        float sv = msk ? -1e30f : s_rc;
        float mx = sv;
        mx = fmaxf(mx, __shfl_xor(mx, 1, 16));
        mx = fmaxf(mx, __shfl_xor(mx, 2, 16));
        mx = fmaxf(mx, __shfl_xor(mx, 4, 16));
        mx = fmaxf(mx, __shfl_xor(mx, 8, 16));
        float e = msk ? 0.f : expf(sv - mx);
        float sum = e;
        sum += __shfl_xor(sum, 1, 16);
        sum += __shfl_xor(sum, 2, 16);
        sum += __shfl_xor(sum, 4, 16);
        sum += __shfl_xor(sum, 8, 16);
        float p = e / sum;
        p_lds[t] = p;
        attn_out[midx] = p;
    }
    __syncthreads();

    const int r2 = t >> 4, tc = t & 15;
    f32x4 acc[8];
#pragma unroll
    for (int j = 0; j < 8; ++j) acc[j] = (f32x4){0.f, 0.f, 0.f, 0.f};
    for (int c2 = 0; c2 < 16; ++c2) {
        float pw = p_lds[r2 * 16 + c2];
        const f32x4* xrow = (const f32x4*)(&xs[c2 * XS_STRIDE]);
#pragma unroll
        for (int j = 0; j < 8; ++j) acc[j] += pw * xrow[tc + 16 * j];
    }

    const f32x4* xme = (const f32x4*)(&xs[r2 * XS_STRIDE]);
    f32x4 vv[8];
    float s1 = 0.f, s2 = 0.f;
#pragma unroll
    for (int j = 0; j < 8; ++j) {
        f32x4 v = xme[tc + 16 * j] + acc[j];
        vv[j] = v;
        s1 += v.x + v.y + v.z + v.w;
        s2 += v.x * v.x + v.y * v.y + v.z * v.z + v.w * v.w;
    }
    s1 += __shfl_xor(s1, 1, 16); s2 += __shfl_xor(s2, 1, 16);
    s1 += __shfl_xor(s1, 2, 16); s2 += __shfl_xor(s2, 2, 16);
    s1 += __shfl_xor(s1, 4, 16); s2 += __shfl_xor(s2, 4, 16);
    s1 += __shfl_xor(s1, 8, 16); s2 += __shfl_xor(s2, 8, 16);
    float mu = s1 * (1.f / 512.f);
    float var = s2 * (1.f / 512.f) - mu * mu;
    float inv = rsqrtf(var + 1e-5f);

    unsigned short* hrow = hbf + (size_t)(b * NTOK + r2) * DDIM;
#pragma unroll
    for (int j = 0; j < 8; ++j) {
        int u = tc + 16 * j;
        f32x4 gv = ((const f32x4*)g1)[u];
        f32x4 bv = ((const f32x4*)b1)[u];
        f32x4 o = (vv[j] - mu) * inv * gv + bv;
        uint2 pk;
        pk.x = (unsigned)f2bf(o.x) | ((unsigned)f2bf(o.y) << 16);
        pk.y = (unsigned)f2bf(o.z) | ((unsigned)f2bf(o.w) << 16);
        *(uint2*)(hrow + u * 4) = pk;
    }
}

// ---------- FFN1: 8-phase 256x256 GEMM, one barrier per phase ----------
#define PH_READA(Al, Q) { short8 a00, a01, a10, a11; \
    a00 = *(const short8*)((Al) + aoffs[2*(Q)]   + kk2[0]); \
    a01 = *(const short8*)((Al) + aoffs[2*(Q)]   + kk2[1]); \
    a10 = *(const short8*)((Al) + aoffs[2*(Q)+1] + kk2[0]); \
    a11 = *(const short8*)((Al) + aoffs[2*(Q)+1] + kk2[1]);

#define PH_READB(Bl) \
    bb00 = *(const short8*)((Bl) + boffs[0] + kk2[0]); \
    bb01 = *(const short8*)((Bl) + boffs[0] + kk2[1]); \
    bb10 = *(const short8*)((Bl) + boffs[1] + kk2[0]); \
    bb11 = *(const short8*)((Bl) + boffs[1] + kk2[1]); \
    bb20 = *(const short8*)((Bl) + boffs[2] + kk2[0]); \
    bb21 = *(const short8*)((Bl) + boffs[2] + kk2[1]); \
    bb30 = *(const short8*)((Bl) + boffs[3] + kk2[0]); \
    bb31 = *(const short8*)((Bl) + boffs[3] + kk2[1]);

#define PH_MFMA(Q) \
    asm volatile("s_waitcnt lgkmcnt(0)" ::: "memory"); \
    __builtin_amdgcn_sched_barrier(0); \
    __builtin_amdgcn_s_setprio(1); \
    acc[2*(Q)][0]   = mfma16(a00, bb00, acc[2*(Q)][0]); \
    acc[2*(Q)][0]   = mfma16(a01, bb01, acc[2*(Q)][0]); \
    acc[2*(Q)][1]   = mfma16(a00, bb10, acc[2*(Q)][1]); \
    acc[2*(Q)][1]   = mfma16(a01, bb11, acc[2*(Q)][1]); \
    acc[2*(Q)][2]   = mfma16(a00, bb20, acc[2*(Q)][2]); \
    acc[2*(Q)][2]   = mfma16(a01, bb21, acc[2*(Q)][2]); \
    acc[2*(Q)][3]   = mfma16(a00, bb30, acc[2*(Q)][3]); \
    acc[2*(Q)][3]   = mfma16(a01, bb31, acc[2*(Q)][3]); \
    acc[2*(Q)+1][0] = mfma16(a10, bb00, acc[2*(Q)+1][0]); \
    acc[2*(Q)+1][0] = mfma16(a11, bb01, acc[2*(Q)+1][0]); \
    acc[2*(Q)+1][1] = mfma16(a10, bb10, acc[2*(Q)+1][1]); \
    acc[2*(Q)+1][1] = mfma16(a11, bb11, acc[2*(Q)+1][1]); \
    acc[2*(Q)+1][2] = mfma16(a10, bb20, acc[2*(Q)+1][2]); \
    acc[2*(Q)+1][2] = mfma16(a11, bb21, acc[2*(Q)+1][2]); \
    acc[2*(Q)+1][3] = mfma16(a10, bb30, acc[2*(Q)+1][3]); \
    acc[2*(Q)+1][3] = mfma16(a11, bb31, acc[2*(Q)+1][3]); \
    __builtin_amdgcn_s_setprio(0);

#define PH_END  __builtin_amdgcn_s_barrier(); }

#define GEMM_BODY(MORE) \
        PH_READA(A0lds, 0) PH_READB(B0lds) \
        stageA(v, A1lds, 0); stageA(v, A1lds, 1); \
        PH_MFMA(0) PH_END \
        PH_READA(A0lds, 1) \
        if (MORE) stageB(u2, B0lds, 0); \
        PH_MFMA(1) PH_END \
        PH_READA(A0lds, 2) \
        if (MORE) stageB(u2, B0lds, 1); \
        PH_MFMA(2) PH_END \
        PH_READA(A0lds, 3) \
        PH_MFMA(3) \
        if (MORE) { asm volatile("s_waitcnt vmcnt(4)" ::: "memory"); } \
        else      { asm volatile("s_waitcnt vmcnt(0)" ::: "memory"); } \
        PH_END \
        PH_READA(A1lds, 0) PH_READB(B1lds) \
        if (MORE) stageA(u2, A0lds, 0); \
        PH_MFMA(0) PH_END \
        PH_READA(A1lds, 1) \
        if (MORE) stageA(u2, A0lds, 1); \
        PH_MFMA(1) PH_END \
        PH_READA(A1lds, 2) \
        if (MORE) stageB(v2, B1lds, 0); \
        PH_MFMA(2) PH_END \
        PH_READA(A1lds, 3) \
        if (MORE) stageB(v2, B1lds, 1); \
        PH_MFMA(3) \
        if (MORE) { asm volatile("s_waitcnt vmcnt(4)" ::: "memory"); } \
        PH_END

__global__ __launch_bounds__(512, 2) void gemm1_kernel(
    const unsigned short* __restrict__ A, const unsigned short* __restrict__ Bw,
    const float* __restrict__ bias, unsigned short* __restrict__ Cbf) {
    constexpr int K = 512;
    constexpr int NT = K / 64;
    constexpr int NXT = 8;                 // N = 2048
    constexpr int NC = 2048;

    extern __shared__ unsigned short lds[];
    unsigned short* A0lds = lds;
    unsigned short* B0lds = lds + 16384;
    unsigned short* A1lds = lds + 32768;
    unsigned short* B1lds = lds + 49152;

    const int nwg = (int)gridDim.x;
    const int orig = (int)blockIdx.x;
    const int q8 = nwg >> 3, r8 = nwg & 7;
    const int xcd = orig & 7, idx = orig >> 3;
    const int w = (xcd < r8 ? xcd * (q8 + 1) : r8 * (q8 + 1) + (xcd - r8) * q8) + idx;
    const int mt_i = w / NXT, nt_i = w % NXT;
    const size_t arow0 = (size_t)mt_i * 256;
    const int n0 = nt_i * 256;

    const int tid = threadIdx.x;
    const int l = tid & 63, wv = tid >> 6;
    const int wm = wv >> 2, wn = wv & 3;
    const int lr = l & 15, lq = l >> 4;

    const int srow = tid >> 3;
    const int skb = ((((tid & 7) << 4) ^ ((srow & 7) << 4)) >> 1);

    const int sw = (lr & 7) << 4;
    int kk2[2];
    kk2[0] = ((lq * 16) ^ sw) >> 1;
    kk2[1] = ((64 + lq * 16) ^ sw) >> 1;
    int aoffs[8], boffs[4];
#pragma unroll
    for (int mf = 0; mf < 8; ++mf) aoffs[mf] = (wm * 128 + mf * 16 + lr) * 64;
#pragma unroll
    for (int nf = 0; nf < 4; ++nf) boffs[nf] = (wn * 64 + nf * 16 + lr) * 64;

    f32x4 acc[8][4];
#pragma unroll
    for (int i = 0; i < 8; ++i)
#pragma unroll
        for (int j = 0; j < 4; ++j) acc[i][j] = (f32x4){0.f, 0.f, 0.f, 0.f};

    short8 bb00, bb01, bb10, bb11, bb20, bb21, bb30, bb31;

    const unsigned short* Ath = A + (arow0 + srow) * (size_t)K + skb;
    const unsigned short* Bth = Bw + ((size_t)n0 + srow) * K + skb;

    auto stageA = [&](int tile, unsigned short* dst, int half) {
        const unsigned short* g = Ath + (size_t)half * (128 * K) + tile * 64;
        unsigned short* d = dst + half * 8192 + tid * 8;
        GLOAD16(g, d);
        GLOAD16(g + (size_t)64 * K, d + 4096);
    };
    auto stageB = [&](int tile, unsigned short* dst, int half) {
        const unsigned short* g = Bth + (size_t)half * (128 * K) + tile * 64;
        unsigned short* d = dst + half * 8192 + tid * 8;
        GLOAD16(g, d);
        GLOAD16(g + (size_t)64 * K, d + 4096);
    };

    stageB(0, B0lds, 0);
    stageB(0, B0lds, 1);
    stageA(0, A0lds, 0);
    stageA(0, A0lds, 1);
    stageB(1, B1lds, 0);
    stageB(1, B1lds, 1);
    asm volatile("s_waitcnt vmcnt(4)" ::: "memory");
    __builtin_amdgcn_s_barrier();

#pragma unroll 1
    for (int t = 0; t < NT / 2 - 1; ++t) {
        const int v = 2 * t + 1, u2 = 2 * t + 2, v2 = 2 * t + 3;
        GEMM_BODY(1)
    }
    {
        const int t = NT / 2 - 1;
        const int v = 2 * t + 1, u2 = 2 * t + 2, v2 = 2 * t + 3;
        (void)u2; (void)v2;
        GEMM_BODY(0)
    }

    // ---- epilogue: relu+bias, PERMUTED t1 store (col' = lr*4 + nf within the
    // wn-64-group) -> one 8-B uint2 per (mf,qq): 32 stores/thread vs 128 scalar.
    float bv[4];
#pragma unroll
    for (int nf = 0; nf < 4; ++nf) bv[nf] = bias[n0 + wn * 64 + nf * 16 + lr];

#pragma unroll
    for (int mf = 0; mf < 8; ++mf) {
#pragma unroll
        for (int qq = 0; qq < 4; ++qq) {
            long row = (long)arow0 + wm * 128 + mf * 16 + lq * 4 + qq;
            unsigned short o0 = f2bf(fmaxf(acc[mf][0][qq] + bv[0], 0.f));
            unsigned short o1 = f2bf(fmaxf(acc[mf][1][qq] + bv[1], 0.f));
            unsigned short o2 = f2bf(fmaxf(acc[mf][2][qq] + bv[2], 0.f));
            unsigned short o3 = f2bf(fmaxf(acc[mf][3][qq] + bv[3], 0.f));
            uint2 pk;
            pk.x = (unsigned)o0 | ((unsigned)o1 << 16);
            pk.y = (unsigned)o2 | ((unsigned)o3 << 16);
            *(uint2*)(&Cbf[(size_t)row * NC + n0 + wn * 64 + lr * 4]) = pk;
        }
    }
}

// ---------- FFN2 + LN2 fused: y = LN(t1 @ W2^T + bW2 + h) ----------
// Round-8 proven version (183 us): BM=128 x BN=512, 8 waves (2m x 4n),
// BALANCED phases: A-frags (8 reads) at p0/p4 in regs; B streams 4 reads/phase.
// t1 and W2T both carry the SAME permuted k-order -> pairing preserved.

#define RD_A2(Al) \
    areg[0][0] = *(const short8*)((Al) + aoffs2[0] + kk2[0]); \
    areg[0][1] = *(const short8*)((Al) + aoffs2[0] + kk2[1]); \
    areg[1][0] = *(const short8*)((Al) + aoffs2[1] + kk2[0]); \
    areg[1][1] = *(const short8*)((Al) + aoffs2[1] + kk2[1]); \
    areg[2][0] = *(const short8*)((Al) + aoffs2[2] + kk2[0]); \
    areg[2][1] = *(const short8*)((Al) + aoffs2[2] + kk2[1]); \
    areg[3][0] = *(const short8*)((Al) + aoffs2[3] + kk2[0]); \
    areg[3][1] = *(const short8*)((Al) + aoffs2[3] + kk2[1]);

#define RD_B2(Bl, q) \
    bq00 = *(const short8*)((Bl) + boffs2[2*(q)]   + kk2[0]); \
    bq01 = *(const short8*)((Bl) + boffs2[2*(q)]   + kk2[1]); \
    bq10 = *(const short8*)((Bl) + boffs2[2*(q)+1] + kk2[0]); \
    bq11 = *(const short8*)((Bl) + boffs2[2*(q)+1] + kk2[1]);

#define MM_Q2(q) \
    asm volatile("s_waitcnt lgkmcnt(0)" ::: "memory"); \
    __builtin_amdgcn_sched_barrier(0); \
    __builtin_amdgcn_s_setprio(1); \
    _Pragma("unroll") \
    for (int mf = 0; mf < 4; ++mf) { \
        acc[mf][2*(q)]   = mfma16(areg[mf][0], bq00, acc[mf][2*(q)]); \
        acc[mf][2*(q)]   = mfma16(areg[mf][1], bq01, acc[mf][2*(q)]); \
        acc[mf][2*(q)+1] = mfma16(areg[mf][0], bq10, acc[mf][2*(q)+1]); \
        acc[mf][2*(q)+1] = mfma16(areg[mf][1], bq11, acc[mf][2*(q)+1]); \
    } \
    __builtin_amdgcn_s_setprio(0);

#define BAR2 __builtin_amdgcn_s_barrier();

#define BODY2(MORE) \
        RD_B2(B0l, 0) \
        RD_A2(A0l) \
        stageB(v, B1l, 0); \
        MM_Q2(0) BAR2 \
        RD_B2(B0l, 1) \
        stageB(v, B1l, 1); \
        if (MORE) stageA(u2, A0l); \
        MM_Q2(1) BAR2 \
        RD_B2(B0l, 2) \
        MM_Q2(2) BAR2 \
        RD_B2(B0l, 3) \
        MM_Q2(3) \
        if (MORE) { asm volatile("s_waitcnt vmcnt(2)" ::: "memory"); } \
        else      { asm volatile("s_waitcnt vmcnt(0)" ::: "memory"); } \
        BAR2 \
        RD_B2(B1l, 0) \
        RD_A2(A1l) \
        if (MORE) stageB(u2, B0l, 0); \
        MM_Q2(0) BAR2 \
        RD_B2(B1l, 1) \
        if (MORE) { stageB(u2, B0l, 1); stageA(v2, A1l); } \
        MM_Q2(1) BAR2 \
        RD_B2(B1l, 2) \
        MM_Q2(2) BAR2 \
        RD_B2(B1l, 3) \
        MM_Q2(3) \
        if (MORE) { asm volatile("s_waitcnt vmcnt(2)" ::: "memory"); } \
        else      { asm volatile("s_waitcnt vmcnt(0)" ::: "memory"); } \
        BAR2

__global__ __launch_bounds__(512, 2) void gemm2ln_kernel(
    const unsigned short* __restrict__ A,      // t1 chunk [rows][2048] (perm-k)
    const unsigned short* __restrict__ Bw,     // W2T [512][2048] (perm-k)
    const float* __restrict__ bias,            // bW2
    const unsigned short* __restrict__ hres,   // h bf16 (full, global rows)
    const float* __restrict__ g2, const float* __restrict__ b2,
    float* __restrict__ y, long out_row0) {
    constexpr int K = 2048;
    constexpr int NT = K / 64;                 // 32 K-tiles

    extern __shared__ unsigned short lds[];
    unsigned short* A0l = lds;                 // [128][64]
    unsigned short* A1l = lds + 8192;
    unsigned short* B0l = lds + 16384;         // [512][64]
    unsigned short* B1l = lds + 49152;

    const int nwg = (int)gridDim.x;
    const int orig = (int)blockIdx.x;
    const int q8 = nwg >> 3, r8 = nwg & 7;
    const int xcd = orig & 7, idx = orig >> 3;
    const int w = (xcd < r8 ? xcd * (q8 + 1) : r8 * (q8 + 1) + (xcd - r8) * q8) + idx;
    const size_t arow0 = (size_t)w * 128;

    const int tid = threadIdx.x;
    const int l = tid & 63, wv = tid >> 6;
    const int wm = wv & 1, wn = wv >> 1;       // 2 m-waves x 4 n-waves
    const int lr = l & 15, lq = l >> 4;

    const int srow = tid >> 3;
    const int skb = ((((tid & 7) << 4) ^ ((srow & 7) << 4)) >> 1);

    const int sw = (lr & 7) << 4;
    int kk2[2];
    kk2[0] = ((lq * 16) ^ sw) >> 1;
    kk2[1] = ((64 + lq * 16) ^ sw) >> 1;
    int aoffs2[4], boffs2[8];
#pragma unroll
    for (int mf = 0; mf < 4; ++mf) aoffs2[mf] = (wm * 64 + mf * 16 + lr) * 64;
#pragma unroll
    for (int nf = 0; nf < 8; ++nf) boffs2[nf] = (wn * 128 + nf * 16 + lr) * 64;

    f32x4 acc[4][8];
#pragma unroll
    for (int i = 0; i < 4; ++i)
#pragma unroll
        for (int j = 0; j < 8; ++j) acc[i][j] = (f32x4){0.f, 0.f, 0.f, 0.f};

    short8 areg[4][2];
    short8 bq00, bq01, bq10, bq11;

    const unsigned short* Ath = A + (arow0 + srow) * (size_t)K + skb;
    const unsigned short* Bth = Bw + (size_t)srow * K + skb;

    auto stageA = [&](int tile, unsigned short* dst) {
        const unsigned short* g = Ath + tile * 64;
        unsigned short* d = dst + tid * 8;
        GLOAD16(g, d);
        GLOAD16(g + (size_t)64 * K, d + 4096);
    };
    auto stageB = [&](int tile, unsigned short* dst, int half) {
        const unsigned short* g = Bth + (size_t)(half * 256) * K + tile * 64;
        unsigned short* d = dst + half * 16384 + tid * 8;
#pragma unroll
        for (int i = 0; i < 4; ++i)
            GLOAD16(g + (size_t)(64 * i) * K, d + 4096 * i);
    };

    // prologue: A(0)[2], B(0)h0[4], B(0)h1[4], A(1)[2]; wait 10 oldest -> vmcnt(2)
    stageA(0, A0l);
    stageB(0, B0l, 0);
    stageB(0, B0l, 1);
    stageA(1, A1l);
    asm volatile("s_waitcnt vmcnt(2)" ::: "memory");
    __builtin_amdgcn_s_barrier();

#pragma unroll 1
    for (int t = 0; t < NT / 2 - 1; ++t) {
        const int v = 2 * t + 1, u2 = 2 * t + 2, v2 = 2 * t + 3;
        BODY2(1)
    }
    {
        const int t = NT / 2 - 1;
        const int v = 2 * t + 1, u2 = 2 * t + 2, v2 = 2 * t + 3;
        (void)u2; (void)v2;
        BODY2(0)
    }

    // ---- epilogue: bias + bf16-h residual, row LN across block, write y ----
    float* red = (float*)lds;                  // [sum:4x128][sq:4x128] floats
    float bv2[8], gv2[8], bb2[8];
#pragma unroll
    for (int nf = 0; nf < 8; ++nf) {
        int col = wn * 128 + nf * 16 + lr;
        bv2[nf] = bias[col];
        gv2[nf] = g2[col];
        bb2[nf] = b2[col];
    }

#pragma unroll
    for (int mf = 0; mf < 4; ++mf) {
#pragma unroll
        for (int qq = 0; qq < 4; ++qq) {
            int lrow = wm * 64 + mf * 16 + lq * 4 + qq;
            long grow = out_row0 + (long)arow0 + lrow;
            const unsigned short* hr = hres + (size_t)grow * 512 + wn * 128 + lr;
            float s = 0.f, s2 = 0.f;
#pragma unroll
            for (int nf = 0; nf < 8; ++nf) {
                float z = acc[mf][nf][qq] + bv2[nf] + bf2f(hr[nf * 16]);
                acc[mf][nf][qq] = z;
                s += z;
                s2 += z * z;
            }
            s += __shfl_xor(s, 1, 16); s2 += __shfl_xor(s2, 1, 16);
            s += __shfl_xor(s, 2, 16); s2 += __shfl_xor(s2, 2, 16);
            s += __shfl_xor(s, 4, 16); s2 += __shfl_xor(s2, 4, 16);
            s += __shfl_xor(s, 8, 16); s2 += __shfl_xor(s2, 8, 16);
            if (lr == 0) {
                red[wn * 128 + lrow] = s;
                red[512 + wn * 128 + lrow] = s2;
            }
        }
    }
    __syncthreads();

#pragma unroll
    for (int mf = 0; mf < 4; ++mf) {
#pragma unroll
        for (int qq = 0; qq < 4; ++qq) {
            int lrow = wm * 64 + mf * 16 + lq * 4 + qq;
            long grow = out_row0 + (long)arow0 + lrow;
            float s = red[lrow] + red[128 + lrow] + red[256 + lrow] + red[384 + lrow];
            float s2 = red[512 + lrow] + red[640 + lrow] + red[768 + lrow] + red[896 + lrow];
            float mu = s * (1.f / 512.f);
            float var = s2 * (1.f / 512.f) - mu * mu;
            float inv = rsqrtf(var + 1e-5f);
            float* yr = y + (size_t)grow * 512 + wn * 128 + lr;
#pragma unroll
            for (int nf = 0; nf < 8; ++nf)
                yr[nf * 16] = (acc[mf][nf][qq] - mu) * inv * gv2[nf] + bb2[nf];
        }
    }
}

// ---------- host ----------
extern "C" void kernel_launch(void* const* d_in, const int* in_sizes, int n_in,
                              void* d_out, int out_size, void* d_ws, size_t ws_size,
                              hipStream_t stream) {
    const float* x = (const float*)d_in[0];
    const void* mask = d_in[1];
    const float* g1 = (const float*)d_in[2];
    const float* b1 = (const float*)d_in[3];
    const float* g2 = (const float*)d_in[4];
    const float* b2 = (const float*)d_in[5];
    const float* W1 = (const float*)d_in[6];
    const float* bW1 = (const float*)d_in[7];
    const float* W2 = (const float*)d_in[8];
    const float* bW2 = (const float*)d_in[9];

    float* y = (float*)d_out;
    float* attn = y + Y_ELEMS;
    char* ws = (char*)d_ws;
    unsigned short* W1T = (unsigned short*)(ws);                 // 2 MiB  [2048][512]
    unsigned short* W2T = (unsigned short*)(ws + 2097152);       // 2 MiB  [512][2048] perm-k
    int* flag = (int*)(ws + 4194304);
    unsigned short* h = (unsigned short*)(ws + 4194560);         // 64 MiB [65536][512] bf16
    unsigned short* t1 = (unsigned short*)(ws + 71303424ULL);    // [chunk*256][2048] bf16 perm-k

    hipFuncSetAttribute((const void*)gemm1_kernel,
                        hipFuncAttributeMaxDynamicSharedMemorySize, 131072);
    hipFuncSetAttribute((const void*)gemm2ln_kernel,
                        hipFuncAttributeMaxDynamicSharedMemorySize, 163840);

    long cap256 = ((long)ws_size - 71303424L) / (256L * 2048L * 2L);
    if (cap256 < 1) cap256 = 1;
    if (cap256 > 256) cap256 = 256;

    transpose_kernel<<<dim3(64, 16), dim3(256), 0, stream>>>(W1, W1T, 512, 2048, 0);
    transpose_kernel<<<dim3(16, 64), dim3(256), 0, stream>>>(W2, W2T, 2048, 512, 1);
    detect_kernel<<<1, 256, 0, stream>>>((const unsigned char*)mask, flag);
    stage1_kernel<<<4096, 256, 0, stream>>>(x, (const unsigned char*)mask, (const int*)mask,
                                            flag, g1, b1, attn, h);
    for (long t0 = 0; t0 < 256; t0 += cap256) {
        long mt = (256 - t0 < cap256) ? (256 - t0) : cap256;
        long row0 = t0 * 256;
        gemm1_kernel<<<dim3((unsigned)(8 * mt)), 512, 131072, stream>>>(
            h + (size_t)row0 * 512, W1T, bW1, t1);
        gemm2ln_kernel<<<dim3((unsigned)(2 * mt)), 512, 163840, stream>>>(
            t1, W2T, bW2, h, g2, b2, y, row0);
    }
}

// Round 12
// 391.467 us; speedup vs baseline: 1.1868x; 1.0048x over previous
//
#include <hip/hip_runtime.h>

// ---------- types & helpers ----------
typedef float  f32x4 __attribute__((ext_vector_type(4)));
typedef short  short8 __attribute__((ext_vector_type(8)));

__device__ __forceinline__ unsigned short f2bf(float f) {
    unsigned u = __builtin_bit_cast(unsigned, f);
    unsigned r = u + 0x7FFFu + ((u >> 16) & 1u);
    return (unsigned short)(r >> 16);
}
__device__ __forceinline__ float bf2f(unsigned short b) {
    return __builtin_bit_cast(float, (unsigned)b << 16);
}

__device__ __forceinline__ f32x4 mfma16(short8 a, short8 b, f32x4 c) {
    return __builtin_amdgcn_mfma_f32_16x16x32_bf16(a, b, c, 0, 0, 0);
}

#define GLOAD16(gp, lp) \
    __builtin_amdgcn_global_load_lds((const __attribute__((address_space(1))) unsigned int*)(gp), \
                                     (__attribute__((address_space(3))) unsigned int*)(lp), 16, 0, 0)

// ---------- constants ----------
#define BT   4096
#define NTOK 16
#define DDIM 512
#define Y_ELEMS 33554432ULL        // BT*NTOK*DDIM
#define XS_STRIDE 516

// ---------- weight transpose fp32 [R][C] -> bf16 [C][R], optional k-perm ----------
// perm=1: within each 64-wide k-group, k' = (k&15)*4 + ((k>>4)&3)  — matches
// gemm1's permuted t1 store so GEMM2 pairs t1[r][k] with W2T[n][k] consistently.
__global__ __launch_bounds__(256) void transpose_kernel(const float* __restrict__ in,
                                                        unsigned short* __restrict__ out,
                                                        int R, int C, int perm) {
    __shared__ float tile[32][33];
    const int tx = threadIdx.x & 31, ty = threadIdx.x >> 5;
    const int c0 = blockIdx.x * 32, r0 = blockIdx.y * 32;
#pragma unroll
    for (int i = 0; i < 4; ++i)
        tile[ty + 8 * i][tx] = in[(size_t)(r0 + ty + 8 * i) * C + c0 + tx];
    __syncthreads();
    const int k = r0 + tx;
    const int kp = perm ? ((k & ~63) | ((k & 15) << 2) | ((k >> 4) & 3)) : k;
#pragma unroll
    for (int i = 0; i < 4; ++i)
        out[(size_t)(c0 + ty + 8 * i) * R + kp] = f2bf(tile[tx][ty + 8 * i]);
}

// ---------- mask dtype detection ----------
__global__ void detect_kernel(const unsigned char* __restrict__ m, int* __restrict__ flag) {
    __shared__ int any;
    if (threadIdx.x == 0) any = 0;
    __syncthreads();
    int loc = 0;
    for (int i = threadIdx.x; i < 4096; i += 256)
        if (i & 3) loc |= m[i];
    if (loc) atomicOr(&any, 1);
    __syncthreads();
    if (threadIdx.x == 0) *flag = any ? 1 : 0;
}

// ---------- stage 1 (pure fp32): scores, softmax, p@x, LN1 -> h (bf16 only) ----------
__global__ __launch_bounds__(256) void stage1_kernel(
    const float* __restrict__ x,
    const unsigned char* __restrict__ mask_u8, const int* __restrict__ mask_i32,
    const int* __restrict__ flagp,
    const float* __restrict__ g1, const float* __restrict__ b1,
    float* __restrict__ attn_out, unsigned short* __restrict__ hbf) {
    __shared__ float xs[NTOK * XS_STRIDE];
    __shared__ float p_lds[256];

    const int b = blockIdx.x, t = threadIdx.x;
    const float* xb = x + (size_t)b * (NTOK * DDIM);

#pragma unroll
    for (int i = 0; i < 8; ++i) {
        int s = t + 256 * i;
        int r = s >> 7, c4 = s & 127;
        f32x4 v = ((const f32x4*)xb)[s];
        *(f32x4*)(&xs[r * XS_STRIDE + c4 * 4]) = v;
    }
    __syncthreads();

    const int r = t >> 4, c = t & 15;
    {
        const f32x4* xr = (const f32x4*)(&xs[r * XS_STRIDE]);
        const f32x4* xc = (const f32x4*)(&xs[c * XS_STRIDE]);
        f32x4 d4 = {0.f, 0.f, 0.f, 0.f};
#pragma unroll 8
        for (int u = 0; u < 128; ++u) d4 += xr[u] * xc[u];
        float s_rc = (d4.x + d4.y + d4.z + d4.w) * 0.04419417382415922f;

        const int flag = *flagp;
        size_t midx = (size_t)b * 256 + t;
        bool msk = flag ? (mask_u8[midx] != 0) : (mask_i32[midx] != 0);
        float sv = msk ? -1e30f : s_rc;
        float mx = sv;
        mx = fmaxf(mx, __shfl_xor(mx, 1, 16));
        mx = fmaxf(mx, __shfl_xor(mx, 2, 16));
        mx = fmaxf(mx, __shfl_xor(mx, 4, 16));
        mx = fmaxf(mx, __shfl_xor(mx, 8, 16));
        float e = msk ? 0.f : expf(sv - mx);
        float sum = e;
        sum += __shfl_xor(sum, 1, 16);
        sum += __shfl_xor(sum, 2, 16);
        sum += __shfl_xor(sum, 4, 16);
        sum += __shfl_xor(sum, 8, 16);
        float p = e / sum;
        p_lds[t] = p;
        attn_out[midx] = p;
    }
    __syncthreads();

    const int r2 = t >> 4, tc = t & 15;
    f32x4 acc[8];
#pragma unroll
    for (int j = 0; j < 8; ++j) acc[j] = (f32x4){0.f, 0.f, 0.f, 0.f};
    for (int c2 = 0; c2 < 16; ++c2) {
        float pw = p_lds[r2 * 16 + c2];
        const f32x4* xrow = (const f32x4*)(&xs[c2 * XS_STRIDE]);
#pragma unroll
        for (int j = 0; j < 8; ++j) acc[j] += pw * xrow[tc + 16 * j];
    }

    const f32x4* xme = (const f32x4*)(&xs[r2 * XS_STRIDE]);
    f32x4 vv[8];
    float s1 = 0.f, s2 = 0.f;
#pragma unroll
    for (int j = 0; j < 8; ++j) {
        f32x4 v = xme[tc + 16 * j] + acc[j];
        vv[j] = v;
        s1 += v.x + v.y + v.z + v.w;
        s2 += v.x * v.x + v.y * v.y + v.z * v.z + v.w * v.w;
    }
    s1 += __shfl_xor(s1, 1, 16); s2 += __shfl_xor(s2, 1, 16);
    s1 += __shfl_xor(s1, 2, 16); s2 += __shfl_xor(s2, 2, 16);
    s1 += __shfl_xor(s1, 4, 16); s2 += __shfl_xor(s2, 4, 16);
    s1 += __shfl_xor(s1, 8, 16); s2 += __shfl_xor(s2, 8, 16);
    float mu = s1 * (1.f / 512.f);
    float var = s2 * (1.f / 512.f) - mu * mu;
    float inv = rsqrtf(var + 1e-5f);

    unsigned short* hrow = hbf + (size_t)(b * NTOK + r2) * DDIM;
#pragma unroll
    for (int j = 0; j < 8; ++j) {
        int u = tc + 16 * j;
        f32x4 gv = ((const f32x4*)g1)[u];
        f32x4 bv = ((const f32x4*)b1)[u];
        f32x4 o = (vv[j] - mu) * inv * gv + bv;
        uint2 pk;
        pk.x = (unsigned)f2bf(o.x) | ((unsigned)f2bf(o.y) << 16);
        pk.y = (unsigned)f2bf(o.z) | ((unsigned)f2bf(o.w) << 16);
        *(uint2*)(hrow + u * 4) = pk;
    }
}

// ---------- FFN1: 8-phase 256x256 GEMM, one barrier per phase ----------
// Round-12 change: NO lgkmcnt(0)/sched_barrier(0) pin before the MFMA cluster —
// the compiler emits fine-grained lgkmcnt(N) so ds_reads pipeline into MFMAs
// (m97/m141 evidence: order-pinning defeats the compiler's own scheduling).
#define PH_READA(Al, Q) { short8 a00, a01, a10, a11; \
    a00 = *(const short8*)((Al) + aoffs[2*(Q)]   + kk2[0]); \
    a01 = *(const short8*)((Al) + aoffs[2*(Q)]   + kk2[1]); \
    a10 = *(const short8*)((Al) + aoffs[2*(Q)+1] + kk2[0]); \
    a11 = *(const short8*)((Al) + aoffs[2*(Q)+1] + kk2[1]);

#define PH_READB(Bl) \
    bb00 = *(const short8*)((Bl) + boffs[0] + kk2[0]); \
    bb01 = *(const short8*)((Bl) + boffs[0] + kk2[1]); \
    bb10 = *(const short8*)((Bl) + boffs[1] + kk2[0]); \
    bb11 = *(const short8*)((Bl) + boffs[1] + kk2[1]); \
    bb20 = *(const short8*)((Bl) + boffs[2] + kk2[0]); \
    bb21 = *(const short8*)((Bl) + boffs[2] + kk2[1]); \
    bb30 = *(const short8*)((Bl) + boffs[3] + kk2[0]); \
    bb31 = *(const short8*)((Bl) + boffs[3] + kk2[1]);

#define PH_MFMA(Q) \
    __builtin_amdgcn_s_setprio(1); \
    acc[2*(Q)][0]   = mfma16(a00, bb00, acc[2*(Q)][0]); \
    acc[2*(Q)][0]   = mfma16(a01, bb01, acc[2*(Q)][0]); \
    acc[2*(Q)][1]   = mfma16(a00, bb10, acc[2*(Q)][1]); \
    acc[2*(Q)][1]   = mfma16(a01, bb11, acc[2*(Q)][1]); \
    acc[2*(Q)][2]   = mfma16(a00, bb20, acc[2*(Q)][2]); \
    acc[2*(Q)][2]   = mfma16(a01, bb21, acc[2*(Q)][2]); \
    acc[2*(Q)][3]   = mfma16(a00, bb30, acc[2*(Q)][3]); \
    acc[2*(Q)][3]   = mfma16(a01, bb31, acc[2*(Q)][3]); \
    acc[2*(Q)+1][0] = mfma16(a10, bb00, acc[2*(Q)+1][0]); \
    acc[2*(Q)+1][0] = mfma16(a11, bb01, acc[2*(Q)+1][0]); \
    acc[2*(Q)+1][1] = mfma16(a10, bb10, acc[2*(Q)+1][1]); \
    acc[2*(Q)+1][1] = mfma16(a11, bb11, acc[2*(Q)+1][1]); \
    acc[2*(Q)+1][2] = mfma16(a10, bb20, acc[2*(Q)+1][2]); \
    acc[2*(Q)+1][2] = mfma16(a11, bb21, acc[2*(Q)+1][2]); \
    acc[2*(Q)+1][3] = mfma16(a10, bb30, acc[2*(Q)+1][3]); \
    acc[2*(Q)+1][3] = mfma16(a11, bb31, acc[2*(Q)+1][3]); \
    __builtin_amdgcn_s_setprio(0);

#define PH_END  __builtin_amdgcn_s_barrier(); }

#define GEMM_BODY(MORE) \
        PH_READA(A0lds, 0) PH_READB(B0lds) \
        stageA(v, A1lds, 0); stageA(v, A1lds, 1); \
        PH_MFMA(0) PH_END \
        PH_READA(A0lds, 1) \
        if (MORE) stageB(u2, B0lds, 0); \
        PH_MFMA(1) PH_END \
        PH_READA(A0lds, 2) \
        if (MORE) stageB(u2, B0lds, 1); \
        PH_MFMA(2) PH_END \
        PH_READA(A0lds, 3) \
        PH_MFMA(3) \
        if (MORE) { asm volatile("s_waitcnt vmcnt(4)" ::: "memory"); } \
        else      { asm volatile("s_waitcnt vmcnt(0)" ::: "memory"); } \
        PH_END \
        PH_READA(A1lds, 0) PH_READB(B1lds) \
        if (MORE) stageA(u2, A0lds, 0); \
        PH_MFMA(0) PH_END \
        PH_READA(A1lds, 1) \
        if (MORE) stageA(u2, A0lds, 1); \
        PH_MFMA(1) PH_END \
        PH_READA(A1lds, 2) \
        if (MORE) stageB(v2, B1lds, 0); \
        PH_MFMA(2) PH_END \
        PH_READA(A1lds, 3) \
        if (MORE) stageB(v2, B1lds, 1); \
        PH_MFMA(3) \
        if (MORE) { asm volatile("s_waitcnt vmcnt(4)" ::: "memory"); } \
        PH_END

__global__ __launch_bounds__(512, 2) void gemm1_kernel(
    const unsigned short* __restrict__ A, const unsigned short* __restrict__ Bw,
    const float* __restrict__ bias, unsigned short* __restrict__ Cbf) {
    constexpr int K = 512;
    constexpr int NT = K / 64;
    constexpr int NXT = 8;                 // N = 2048
    constexpr int NC = 2048;

    extern __shared__ unsigned short lds[];
    unsigned short* A0lds = lds;
    unsigned short* B0lds = lds + 16384;
    unsigned short* A1lds = lds + 32768;
    unsigned short* B1lds = lds + 49152;

    const int nwg = (int)gridDim.x;
    const int orig = (int)blockIdx.x;
    const int q8 = nwg >> 3, r8 = nwg & 7;
    const int xcd = orig & 7, idx = orig >> 3;
    const int w = (xcd < r8 ? xcd * (q8 + 1) : r8 * (q8 + 1) + (xcd - r8) * q8) + idx;
    const int mt_i = w / NXT, nt_i = w % NXT;
    const size_t arow0 = (size_t)mt_i * 256;
    const int n0 = nt_i * 256;

    const int tid = threadIdx.x;
    const int l = tid & 63, wv = tid >> 6;
    const int wm = wv >> 2, wn = wv & 3;
    const int lr = l & 15, lq = l >> 4;

    const int srow = tid >> 3;
    const int skb = ((((tid & 7) << 4) ^ ((srow & 7) << 4)) >> 1);

    const int sw = (lr & 7) << 4;
    int kk2[2];
    kk2[0] = ((lq * 16) ^ sw) >> 1;
    kk2[1] = ((64 + lq * 16) ^ sw) >> 1;
    int aoffs[8], boffs[4];
#pragma unroll
    for (int mf = 0; mf < 8; ++mf) aoffs[mf] = (wm * 128 + mf * 16 + lr) * 64;
#pragma unroll
    for (int nf = 0; nf < 4; ++nf) boffs[nf] = (wn * 64 + nf * 16 + lr) * 64;

    f32x4 acc[8][4];
#pragma unroll
    for (int i = 0; i < 8; ++i)
#pragma unroll
        for (int j = 0; j < 4; ++j) acc[i][j] = (f32x4){0.f, 0.f, 0.f, 0.f};

    short8 bb00, bb01, bb10, bb11, bb20, bb21, bb30, bb31;

    const unsigned short* Ath = A + (arow0 + srow) * (size_t)K + skb;
    const unsigned short* Bth = Bw + ((size_t)n0 + srow) * K + skb;

    auto stageA = [&](int tile, unsigned short* dst, int half) {
        const unsigned short* g = Ath + (size_t)half * (128 * K) + tile * 64;
        unsigned short* d = dst + half * 8192 + tid * 8;
        GLOAD16(g, d);
        GLOAD16(g + (size_t)64 * K, d + 4096);
    };
    auto stageB = [&](int tile, unsigned short* dst, int half) {
        const unsigned short* g = Bth + (size_t)half * (128 * K) + tile * 64;
        unsigned short* d = dst + half * 8192 + tid * 8;
        GLOAD16(g, d);
        GLOAD16(g + (size_t)64 * K, d + 4096);
    };

    stageB(0, B0lds, 0);
    stageB(0, B0lds, 1);
    stageA(0, A0lds, 0);
    stageA(0, A0lds, 1);
    stageB(1, B1lds, 0);
    stageB(1, B1lds, 1);
    asm volatile("s_waitcnt vmcnt(4)" ::: "memory");
    __builtin_amdgcn_s_barrier();

#pragma unroll 1
    for (int t = 0; t < NT / 2 - 1; ++t) {
        const int v = 2 * t + 1, u2 = 2 * t + 2, v2 = 2 * t + 3;
        GEMM_BODY(1)
    }
    {
        const int t = NT / 2 - 1;
        const int v = 2 * t + 1, u2 = 2 * t + 2, v2 = 2 * t + 3;
        (void)u2; (void)v2;
        GEMM_BODY(0)
    }

    // ---- epilogue: relu+bias, PERMUTED t1 store (col' = lr*4 + nf within the
    // wn-64-group) -> one 8-B uint2 per (mf,qq).
    float bv[4];
#pragma unroll
    for (int nf = 0; nf < 4; ++nf) bv[nf] = bias[n0 + wn * 64 + nf * 16 + lr];

#pragma unroll
    for (int mf = 0; mf < 8; ++mf) {
#pragma unroll
        for (int qq = 0; qq < 4; ++qq) {
            long row = (long)arow0 + wm * 128 + mf * 16 + lq * 4 + qq;
            unsigned short o0 = f2bf(fmaxf(acc[mf][0][qq] + bv[0], 0.f));
            unsigned short o1 = f2bf(fmaxf(acc[mf][1][qq] + bv[1], 0.f));
            unsigned short o2 = f2bf(fmaxf(acc[mf][2][qq] + bv[2], 0.f));
            unsigned short o3 = f2bf(fmaxf(acc[mf][3][qq] + bv[3], 0.f));
            uint2 pk;
            pk.x = (unsigned)o0 | ((unsigned)o1 << 16);
            pk.y = (unsigned)o2 | ((unsigned)o3 << 16);
            *(uint2*)(&Cbf[(size_t)row * NC + n0 + wn * 64 + lr * 4]) = pk;
        }
    }
}

// ---------- FFN2 + LN2 fused: y = LN(t1 @ W2^T + bW2 + h) ----------
// BM=128 x BN=512, 8 waves (2m x 4n), balanced phases; un-pinned MFMA clusters.

#define RD_A2(Al) \
    areg[0][0] = *(const short8*)((Al) + aoffs2[0] + kk2[0]); \
    areg[0][1] = *(const short8*)((Al) + aoffs2[0] + kk2[1]); \
    areg[1][0] = *(const short8*)((Al) + aoffs2[1] + kk2[0]); \
    areg[1][1] = *(const short8*)((Al) + aoffs2[1] + kk2[1]); \
    areg[2][0] = *(const short8*)((Al) + aoffs2[2] + kk2[0]); \
    areg[2][1] = *(const short8*)((Al) + aoffs2[2] + kk2[1]); \
    areg[3][0] = *(const short8*)((Al) + aoffs2[3] + kk2[0]); \
    areg[3][1] = *(const short8*)((Al) + aoffs2[3] + kk2[1]);

#define RD_B2(Bl, q) \
    bq00 = *(const short8*)((Bl) + boffs2[2*(q)]   + kk2[0]); \
    bq01 = *(const short8*)((Bl) + boffs2[2*(q)]   + kk2[1]); \
    bq10 = *(const short8*)((Bl) + boffs2[2*(q)+1] + kk2[0]); \
    bq11 = *(const short8*)((Bl) + boffs2[2*(q)+1] + kk2[1]);

#define MM_Q2(q) \
    __builtin_amdgcn_s_setprio(1); \
    _Pragma("unroll") \
    for (int mf = 0; mf < 4; ++mf) { \
        acc[mf][2*(q)]   = mfma16(areg[mf][0], bq00, acc[mf][2*(q)]); \
        acc[mf][2*(q)]   = mfma16(areg[mf][1], bq01, acc[mf][2*(q)]); \
        acc[mf][2*(q)+1] = mfma16(areg[mf][0], bq10, acc[mf][2*(q)+1]); \
        acc[mf][2*(q)+1] = mfma16(areg[mf][1], bq11, acc[mf][2*(q)+1]); \
    } \
    __builtin_amdgcn_s_setprio(0);

#define BAR2 __builtin_amdgcn_s_barrier();

#define BODY2(MORE) \
        RD_B2(B0l, 0) \
        RD_A2(A0l) \
        stageB(v, B1l, 0); \
        MM_Q2(0) BAR2 \
        RD_B2(B0l, 1) \
        stageB(v, B1l, 1); \
        if (MORE) stageA(u2, A0l); \
        MM_Q2(1) BAR2 \
        RD_B2(B0l, 2) \
        MM_Q2(2) BAR2 \
        RD_B2(B0l, 3) \
        MM_Q2(3) \
        if (MORE) { asm volatile("s_waitcnt vmcnt(2)" ::: "memory"); } \
        else      { asm volatile("s_waitcnt vmcnt(0)" ::: "memory"); } \
        BAR2 \
        RD_B2(B1l, 0) \
        RD_A2(A1l) \
        if (MORE) stageB(u2, B0l, 0); \
        MM_Q2(0) BAR2 \
        RD_B2(B1l, 1) \
        if (MORE) { stageB(u2, B0l, 1); stageA(v2, A1l); } \
        MM_Q2(1) BAR2 \
        RD_B2(B1l, 2) \
        MM_Q2(2) BAR2 \
        RD_B2(B1l, 3) \
        MM_Q2(3) \
        if (MORE) { asm volatile("s_waitcnt vmcnt(2)" ::: "memory"); } \
        else      { asm volatile("s_waitcnt vmcnt(0)" ::: "memory"); } \
        BAR2

__global__ __launch_bounds__(512, 2) void gemm2ln_kernel(
    const unsigned short* __restrict__ A,      // t1 chunk [rows][2048] (perm-k)
    const unsigned short* __restrict__ Bw,     // W2T [512][2048] (perm-k)
    const float* __restrict__ bias,            // bW2
    const unsigned short* __restrict__ hres,   // h bf16 (full, global rows)
    const float* __restrict__ g2, const float* __restrict__ b2,
    float* __restrict__ y, long out_row0) {
    constexpr int K = 2048;
    constexpr int NT = K / 64;                 // 32 K-tiles

    extern __shared__ unsigned short lds[];
    unsigned short* A0l = lds;                 // [128][64]
    unsigned short* A1l = lds + 8192;
    unsigned short* B0l = lds + 16384;         // [512][64]
    unsigned short* B1l = lds + 49152;

    const int nwg = (int)gridDim.x;
    const int orig = (int)blockIdx.x;
    const int q8 = nwg >> 3, r8 = nwg & 7;
    const int xcd = orig & 7, idx = orig >> 3;
    const int w = (xcd < r8 ? xcd * (q8 + 1) : r8 * (q8 + 1) + (xcd - r8) * q8) + idx;
    const size_t arow0 = (size_t)w * 128;

    const int tid = threadIdx.x;
    const int l = tid & 63, wv = tid >> 6;
    const int wm = wv & 1, wn = wv >> 1;       // 2 m-waves x 4 n-waves
    const int lr = l & 15, lq = l >> 4;

    const int srow = tid >> 3;
    const int skb = ((((tid & 7) << 4) ^ ((srow & 7) << 4)) >> 1);

    const int sw = (lr & 7) << 4;
    int kk2[2];
    kk2[0] = ((lq * 16) ^ sw) >> 1;
    kk2[1] = ((64 + lq * 16) ^ sw) >> 1;
    int aoffs2[4], boffs2[8];
#pragma unroll
    for (int mf = 0; mf < 4; ++mf) aoffs2[mf] = (wm * 64 + mf * 16 + lr) * 64;
#pragma unroll
    for (int nf = 0; nf < 8; ++nf) boffs2[nf] = (wn * 128 + nf * 16 + lr) * 64;

    f32x4 acc[4][8];
#pragma unroll
    for (int i = 0; i < 4; ++i)
#pragma unroll
        for (int j = 0; j < 8; ++j) acc[i][j] = (f32x4){0.f, 0.f, 0.f, 0.f};

    short8 areg[4][2];
    short8 bq00, bq01, bq10, bq11;

    const unsigned short* Ath = A + (arow0 + srow) * (size_t)K + skb;
    const unsigned short* Bth = Bw + (size_t)srow * K + skb;

    auto stageA = [&](int tile, unsigned short* dst) {
        const unsigned short* g = Ath + tile * 64;
        unsigned short* d = dst + tid * 8;
        GLOAD16(g, d);
        GLOAD16(g + (size_t)64 * K, d + 4096);
    };
    auto stageB = [&](int tile, unsigned short* dst, int half) {
        const unsigned short* g = Bth + (size_t)(half * 256) * K + tile * 64;
        unsigned short* d = dst + half * 16384 + tid * 8;
#pragma unroll
        for (int i = 0; i < 4; ++i)
            GLOAD16(g + (size_t)(64 * i) * K, d + 4096 * i);
    };

    // prologue: A(0)[2], B(0)h0[4], B(0)h1[4], A(1)[2]; wait 10 oldest -> vmcnt(2)
    stageA(0, A0l);
    stageB(0, B0l, 0);
    stageB(0, B0l, 1);
    stageA(1, A1l);
    asm volatile("s_waitcnt vmcnt(2)" ::: "memory");
    __builtin_amdgcn_s_barrier();

#pragma unroll 1
    for (int t = 0; t < NT / 2 - 1; ++t) {
        const int v = 2 * t + 1, u2 = 2 * t + 2, v2 = 2 * t + 3;
        BODY2(1)
    }
    {
        const int t = NT / 2 - 1;
        const int v = 2 * t + 1, u2 = 2 * t + 2, v2 = 2 * t + 3;
        (void)u2; (void)v2;
        BODY2(0)
    }

    // ---- epilogue: bias + bf16-h residual, row LN across block, write y ----
    float* red = (float*)lds;                  // [sum:4x128][sq:4x128] floats
    float bv2[8], gv2[8], bb2[8];
#pragma unroll
    for (int nf = 0; nf < 8; ++nf) {
        int col = wn * 128 + nf * 16 + lr;
        bv2[nf] = bias[col];
        gv2[nf] = g2[col];
        bb2[nf] = b2[col];
    }

#pragma unroll
    for (int mf = 0; mf < 4; ++mf) {
#pragma unroll
        for (int qq = 0; qq < 4; ++qq) {
            int lrow = wm * 64 + mf * 16 + lq * 4 + qq;
            long grow = out_row0 + (long)arow0 + lrow;
            const unsigned short* hr = hres + (size_t)grow * 512 + wn * 128 + lr;
            float s = 0.f, s2 = 0.f;
#pragma unroll
            for (int nf = 0; nf < 8; ++nf) {
                float z = acc[mf][nf][qq] + bv2[nf] + bf2f(hr[nf * 16]);
                acc[mf][nf][qq] = z;
                s += z;
                s2 += z * z;
            }
            s += __shfl_xor(s, 1, 16); s2 += __shfl_xor(s2, 1, 16);
            s += __shfl_xor(s, 2, 16); s2 += __shfl_xor(s2, 2, 16);
            s += __shfl_xor(s, 4, 16); s2 += __shfl_xor(s2, 4, 16);
            s += __shfl_xor(s, 8, 16); s2 += __shfl_xor(s2, 8, 16);
            if (lr == 0) {
                red[wn * 128 + lrow] = s;
                red[512 + wn * 128 + lrow] = s2;
            }
        }
    }
    __syncthreads();

#pragma unroll
    for (int mf = 0; mf < 4; ++mf) {
#pragma unroll
        for (int qq = 0; qq < 4; ++qq) {
            int lrow = wm * 64 + mf * 16 + lq * 4 + qq;
            long grow = out_row0 + (long)arow0 + lrow;
            float s = red[lrow] + red[128 + lrow] + red[256 + lrow] + red[384 + lrow];
            float s2 = red[512 + lrow] + red[640 + lrow] + red[768 + lrow] + red[896 + lrow];
            float mu = s * (1.f / 512.f);
            float var = s2 * (1.f / 512.f) - mu * mu;
            float inv = rsqrtf(var + 1e-5f);
            float* yr = y + (size_t)grow * 512 + wn * 128 + lr;
#pragma unroll
            for (int nf = 0; nf < 8; ++nf)
                yr[nf * 16] = (acc[mf][nf][qq] - mu) * inv * gv2[nf] + bb2[nf];
        }
    }
}

// ---------- host ----------
extern "C" void kernel_launch(void* const* d_in, const int* in_sizes, int n_in,
                              void* d_out, int out_size, void* d_ws, size_t ws_size,
                              hipStream_t stream) {
    const float* x = (const float*)d_in[0];
    const void* mask = d_in[1];
    const float* g1 = (const float*)d_in[2];
    const float* b1 = (const float*)d_in[3];
    const float* g2 = (const float*)d_in[4];
    const float* b2 = (const float*)d_in[5];
    const float* W1 = (const float*)d_in[6];
    const float* bW1 = (const float*)d_in[7];
    const float* W2 = (const float*)d_in[8];
    const float* bW2 = (const float*)d_in[9];

    float* y = (float*)d_out;
    float* attn = y + Y_ELEMS;
    char* ws = (char*)d_ws;
    unsigned short* W1T = (unsigned short*)(ws);                 // 2 MiB  [2048][512]
    unsigned short* W2T = (unsigned short*)(ws + 2097152);       // 2 MiB  [512][2048] perm-k
    int* flag = (int*)(ws + 4194304);
    unsigned short* h = (unsigned short*)(ws + 4194560);         // 64 MiB [65536][512] bf16
    unsigned short* t1 = (unsigned short*)(ws + 71303424ULL);    // [chunk*256][2048] bf16 perm-k

    hipFuncSetAttribute((const void*)gemm1_kernel,
                        hipFuncAttributeMaxDynamicSharedMemorySize, 131072);
    hipFuncSetAttribute((const void*)gemm2ln_kernel,
                        hipFuncAttributeMaxDynamicSharedMemorySize, 163840);

    long cap256 = ((long)ws_size - 71303424L) / (256L * 2048L * 2L);
    if (cap256 < 1) cap256 = 1;
    if (cap256 > 256) cap256 = 256;

    transpose_kernel<<<dim3(64, 16), dim3(256), 0, stream>>>(W1, W1T, 512, 2048, 0);
    transpose_kernel<<<dim3(16, 64), dim3(256), 0, stream>>>(W2, W2T, 2048, 512, 1);
    detect_kernel<<<1, 256, 0, stream>>>((const unsigned char*)mask, flag);
    stage1_kernel<<<4096, 256, 0, stream>>>(x, (const unsigned char*)mask, (const int*)mask,
                                            flag, g1, b1, attn, h);
    for (long t0 = 0; t0 < 256; t0 += cap256) {
        long mt = (256 - t0 < cap256) ? (256 - t0) : cap256;
        long row0 = t0 * 256;
        gemm1_kernel<<<dim3((unsigned)(8 * mt)), 512, 131072, stream>>>(
            h + (size_t)row0 * 512, W1T, bW1, t1);
        gemm2ln_kernel<<<dim3((unsigned)(2 * mt)), 512, 163840, stream>>>(
            t1, W2T, bW2, h, g2, b2, y, row0);
    }
}

// Round 13
// 367.839 us; speedup vs baseline: 1.2630x; 1.0642x over previous
//
#include <hip/hip_runtime.h>

// ---------- types & helpers ----------
typedef float  f32x4 __attribute__((ext_vector_type(4)));
typedef short  short8 __attribute__((ext_vector_type(8)));

__device__ __forceinline__ unsigned short f2bf(float f) {
    unsigned u = __builtin_bit_cast(unsigned, f);
    unsigned r = u + 0x7FFFu + ((u >> 16) & 1u);
    return (unsigned short)(r >> 16);
}
__device__ __forceinline__ float bf2f(unsigned short b) {
    return __builtin_bit_cast(float, (unsigned)b << 16);
}

__device__ __forceinline__ f32x4 mfma16(short8 a, short8 b, f32x4 c) {
    return __builtin_amdgcn_mfma_f32_16x16x32_bf16(a, b, c, 0, 0, 0);
}

#define GLOAD16(gp, lp) \
    __builtin_amdgcn_global_load_lds((const __attribute__((address_space(1))) unsigned int*)(gp), \
                                     (__attribute__((address_space(3))) unsigned int*)(lp), 16, 0, 0)

// ---------- constants ----------
#define BT   4096
#define NTOK 16
#define DDIM 512
#define Y_ELEMS 33554432ULL        // BT*NTOK*DDIM
#define XS_STRIDE 516

// ---------- weight transpose fp32 [R][C] -> bf16 [C][R], optional k-perm ----------
// perm=1: within each 64-wide k-group, k' = (k&15)*4 + ((k>>4)&3)  — matches
// gemm1's permuted t1 store so GEMM2 pairs t1[r][k] with W2T[n][k] consistently.
__global__ __launch_bounds__(256) void transpose_kernel(const float* __restrict__ in,
                                                        unsigned short* __restrict__ out,
                                                        int R, int C, int perm) {
    __shared__ float tile[32][33];
    const int tx = threadIdx.x & 31, ty = threadIdx.x >> 5;
    const int c0 = blockIdx.x * 32, r0 = blockIdx.y * 32;
#pragma unroll
    for (int i = 0; i < 4; ++i)
        tile[ty + 8 * i][tx] = in[(size_t)(r0 + ty + 8 * i) * C + c0 + tx];
    __syncthreads();
    const int k = r0 + tx;
    const int kp = perm ? ((k & ~63) | ((k & 15) << 2) | ((k >> 4) & 3)) : k;
#pragma unroll
    for (int i = 0; i < 4; ++i)
        out[(size_t)(c0 + ty + 8 * i) * R + kp] = f2bf(tile[tx][ty + 8 * i]);
}

// ---------- mask dtype detection ----------
__global__ void detect_kernel(const unsigned char* __restrict__ m, int* __restrict__ flag) {
    __shared__ int any;
    if (threadIdx.x == 0) any = 0;
    __syncthreads();
    int loc = 0;
    for (int i = threadIdx.x; i < 4096; i += 256)
        if (i & 3) loc |= m[i];
    if (loc) atomicOr(&any, 1);
    __syncthreads();
    if (threadIdx.x == 0) *flag = any ? 1 : 0;
}

// ---------- stage 1 (pure fp32): scores, softmax, p@x, LN1 -> h (bf16 only) ----------
__global__ __launch_bounds__(256) void stage1_kernel(
    const float* __restrict__ x,
    const unsigned char* __restrict__ mask_u8, const int* __restrict__ mask_i32,
    const int* __restrict__ flagp,
    const float* __restrict__ g1, const float* __restrict__ b1,
    float* __restrict__ attn_out, unsigned short* __restrict__ hbf) {
    __shared__ float xs[NTOK * XS_STRIDE];
    __shared__ float p_lds[256];

    const int b = blockIdx.x, t = threadIdx.x;
    const float* xb = x + (size_t)b * (NTOK * DDIM);

#pragma unroll
    for (int i = 0; i < 8; ++i) {
        int s = t + 256 * i;
        int r = s >> 7, c4 = s & 127;
        f32x4 v = ((const f32x4*)xb)[s];
        *(f32x4*)(&xs[r * XS_STRIDE + c4 * 4]) = v;
    }
    __syncthreads();

    const int r = t >> 4, c = t & 15;
    {
        const f32x4* xr = (const f32x4*)(&xs[r * XS_STRIDE]);
        const f32x4* xc = (const f32x4*)(&xs[c * XS_STRIDE]);
        f32x4 d4 = {0.f, 0.f, 0.f, 0.f};
#pragma unroll 8
        for (int u = 0; u < 128; ++u) d4 += xr[u] * xc[u];
        float s_rc = (d4.x + d4.y + d4.z + d4.w) * 0.04419417382415922f;

        const int flag = *flagp;
        size_t midx = (size_t)b * 256 + t;
        bool msk = flag ? (mask_u8[midx] != 0) : (mask_i32[midx] != 0);
        float sv = msk ? -1e30f : s_rc;
        float mx = sv;
        mx = fmaxf(mx, __shfl_xor(mx, 1, 16));
        mx = fmaxf(mx, __shfl_xor(mx, 2, 16));
        mx = fmaxf(mx, __shfl_xor(mx, 4, 16));
        mx = fmaxf(mx, __shfl_xor(mx, 8, 16));
        float e = msk ? 0.f : expf(sv - mx);
        float sum = e;
        sum += __shfl_xor(sum, 1, 16);
        sum += __shfl_xor(sum, 2, 16);
        sum += __shfl_xor(sum, 4, 16);
        sum += __shfl_xor(sum, 8, 16);
        float p = e / sum;
        p_lds[t] = p;
        attn_out[midx] = p;
    }
    __syncthreads();

    const int r2 = t >> 4, tc = t & 15;
    f32x4 acc[8];
#pragma unroll
    for (int j = 0; j < 8; ++j) acc[j] = (f32x4){0.f, 0.f, 0.f, 0.f};
    for (int c2 = 0; c2 < 16; ++c2) {
        float pw = p_lds[r2 * 16 + c2];
        const f32x4* xrow = (const f32x4*)(&xs[c2 * XS_STRIDE]);
#pragma unroll
        for (int j = 0; j < 8; ++j) acc[j] += pw * xrow[tc + 16 * j];
    }

    const f32x4* xme = (const f32x4*)(&xs[r2 * XS_STRIDE]);
    f32x4 vv[8];
    float s1 = 0.f, s2 = 0.f;
#pragma unroll
    for (int j = 0; j < 8; ++j) {
        f32x4 v = xme[tc + 16 * j] + acc[j];
        vv[j] = v;
        s1 += v.x + v.y + v.z + v.w;
        s2 += v.x * v.x + v.y * v.y + v.z * v.z + v.w * v.w;
    }
    s1 += __shfl_xor(s1, 1, 16); s2 += __shfl_xor(s2, 1, 16);
    s1 += __shfl_xor(s1, 2, 16); s2 += __shfl_xor(s2, 2, 16);
    s1 += __shfl_xor(s1, 4, 16); s2 += __shfl_xor(s2, 4, 16);
    s1 += __shfl_xor(s1, 8, 16); s2 += __shfl_xor(s2, 8, 16);
    float mu = s1 * (1.f / 512.f);
    float var = s2 * (1.f / 512.f) - mu * mu;
    float inv = rsqrtf(var + 1e-5f);

    unsigned short* hrow = hbf + (size_t)(b * NTOK + r2) * DDIM;
#pragma unroll
    for (int j = 0; j < 8; ++j) {
        int u = tc + 16 * j;
        f32x4 gv = ((const f32x4*)g1)[u];
        f32x4 bv = ((const f32x4*)b1)[u];
        f32x4 o = (vv[j] - mu) * inv * gv + bv;
        uint2 pk;
        pk.x = (unsigned)f2bf(o.x) | ((unsigned)f2bf(o.y) << 16);
        pk.y = (unsigned)f2bf(o.z) | ((unsigned)f2bf(o.w) << 16);
        *(uint2*)(hrow + u * 4) = pk;
    }
}

// ---------- FFN1: 8-phase 256x256 GEMM, one barrier per phase (round-12 base) ----------
#define PH_READA(Al, Q) { short8 a00, a01, a10, a11; \
    a00 = *(const short8*)((Al) + aoffs[2*(Q)]   + kk2[0]); \
    a01 = *(const short8*)((Al) + aoffs[2*(Q)]   + kk2[1]); \
    a10 = *(const short8*)((Al) + aoffs[2*(Q)+1] + kk2[0]); \
    a11 = *(const short8*)((Al) + aoffs[2*(Q)+1] + kk2[1]);

#define PH_READB(Bl) \
    bb00 = *(const short8*)((Bl) + boffs[0] + kk2[0]); \
    bb01 = *(const short8*)((Bl) + boffs[0] + kk2[1]); \
    bb10 = *(const short8*)((Bl) + boffs[1] + kk2[0]); \
    bb11 = *(const short8*)((Bl) + boffs[1] + kk2[1]); \
    bb20 = *(const short8*)((Bl) + boffs[2] + kk2[0]); \
    bb21 = *(const short8*)((Bl) + boffs[2] + kk2[1]); \
    bb30 = *(const short8*)((Bl) + boffs[3] + kk2[0]); \
    bb31 = *(const short8*)((Bl) + boffs[3] + kk2[1]);

#define PH_MFMA(Q) \
    __builtin_amdgcn_s_setprio(1); \
    acc[2*(Q)][0]   = mfma16(a00, bb00, acc[2*(Q)][0]); \
    acc[2*(Q)][0]   = mfma16(a01, bb01, acc[2*(Q)][0]); \
    acc[2*(Q)][1]   = mfma16(a00, bb10, acc[2*(Q)][1]); \
    acc[2*(Q)][1]   = mfma16(a01, bb11, acc[2*(Q)][1]); \
    acc[2*(Q)][2]   = mfma16(a00, bb20, acc[2*(Q)][2]); \
    acc[2*(Q)][2]   = mfma16(a01, bb21, acc[2*(Q)][2]); \
    acc[2*(Q)][3]   = mfma16(a00, bb30, acc[2*(Q)][3]); \
    acc[2*(Q)][3]   = mfma16(a01, bb31, acc[2*(Q)][3]); \
    acc[2*(Q)+1][0] = mfma16(a10, bb00, acc[2*(Q)+1][0]); \
    acc[2*(Q)+1][0] = mfma16(a11, bb01, acc[2*(Q)+1][0]); \
    acc[2*(Q)+1][1] = mfma16(a10, bb10, acc[2*(Q)+1][1]); \
    acc[2*(Q)+1][1] = mfma16(a11, bb11, acc[2*(Q)+1][1]); \
    acc[2*(Q)+1][2] = mfma16(a10, bb20, acc[2*(Q)+1][2]); \
    acc[2*(Q)+1][2] = mfma16(a11, bb21, acc[2*(Q)+1][2]); \
    acc[2*(Q)+1][3] = mfma16(a10, bb30, acc[2*(Q)+1][3]); \
    acc[2*(Q)+1][3] = mfma16(a11, bb31, acc[2*(Q)+1][3]); \
    __builtin_amdgcn_s_setprio(0);

#define PH_END  __builtin_amdgcn_s_barrier(); }

#define GEMM_BODY(MORE) \
        PH_READA(A0lds, 0) PH_READB(B0lds) \
        stageA(v, A1lds, 0); stageA(v, A1lds, 1); \
        PH_MFMA(0) PH_END \
        PH_READA(A0lds, 1) \
        if (MORE) stageB(u2, B0lds, 0); \
        PH_MFMA(1) PH_END \
        PH_READA(A0lds, 2) \
        if (MORE) stageB(u2, B0lds, 1); \
        PH_MFMA(2) PH_END \
        PH_READA(A0lds, 3) \
        PH_MFMA(3) \
        if (MORE) { asm volatile("s_waitcnt vmcnt(4)" ::: "memory"); } \
        else      { asm volatile("s_waitcnt vmcnt(0)" ::: "memory"); } \
        PH_END \
        PH_READA(A1lds, 0) PH_READB(B1lds) \
        if (MORE) stageA(u2, A0lds, 0); \
        PH_MFMA(0) PH_END \
        PH_READA(A1lds, 1) \
        if (MORE) stageA(u2, A0lds, 1); \
        PH_MFMA(1) PH_END \
        PH_READA(A1lds, 2) \
        if (MORE) stageB(v2, B1lds, 0); \
        PH_MFMA(2) PH_END \
        PH_READA(A1lds, 3) \
        if (MORE) stageB(v2, B1lds, 1); \
        PH_MFMA(3) \
        if (MORE) { asm volatile("s_waitcnt vmcnt(4)" ::: "memory"); } \
        PH_END

__global__ __launch_bounds__(512, 2) void gemm1_kernel(
    const unsigned short* __restrict__ A, const unsigned short* __restrict__ Bw,
    const float* __restrict__ bias, unsigned short* __restrict__ Cbf) {
    constexpr int K = 512;
    constexpr int NT = K / 64;
    constexpr int NXT = 8;                 // N = 2048
    constexpr int NC = 2048;

    extern __shared__ unsigned short lds[];
    unsigned short* A0lds = lds;
    unsigned short* B0lds = lds + 16384;
    unsigned short* A1lds = lds + 32768;
    unsigned short* B1lds = lds + 49152;

    const int nwg = (int)gridDim.x;
    const int orig = (int)blockIdx.x;
    const int q8 = nwg >> 3, r8 = nwg & 7;
    const int xcd = orig & 7, idx = orig >> 3;
    const int w = (xcd < r8 ? xcd * (q8 + 1) : r8 * (q8 + 1) + (xcd - r8) * q8) + idx;
    const int mt_i = w / NXT, nt_i = w % NXT;
    const size_t arow0 = (size_t)mt_i * 256;
    const int n0 = nt_i * 256;

    const int tid = threadIdx.x;
    const int l = tid & 63, wv = tid >> 6;
    const int wm = wv >> 2, wn = wv & 3;
    const int lr = l & 15, lq = l >> 4;

    const int srow = tid >> 3;
    const int skb = ((((tid & 7) << 4) ^ ((srow & 7) << 4)) >> 1);

    const int sw = (lr & 7) << 4;
    int kk2[2];
    kk2[0] = ((lq * 16) ^ sw) >> 1;
    kk2[1] = ((64 + lq * 16) ^ sw) >> 1;
    int aoffs[8], boffs[4];
#pragma unroll
    for (int mf = 0; mf < 8; ++mf) aoffs[mf] = (wm * 128 + mf * 16 + lr) * 64;
#pragma unroll
    for (int nf = 0; nf < 4; ++nf) boffs[nf] = (wn * 64 + nf * 16 + lr) * 64;

    f32x4 acc[8][4];
#pragma unroll
    for (int i = 0; i < 8; ++i)
#pragma unroll
        for (int j = 0; j < 4; ++j) acc[i][j] = (f32x4){0.f, 0.f, 0.f, 0.f};

    short8 bb00, bb01, bb10, bb11, bb20, bb21, bb30, bb31;

    const unsigned short* Ath = A + (arow0 + srow) * (size_t)K + skb;
    const unsigned short* Bth = Bw + ((size_t)n0 + srow) * K + skb;

    auto stageA = [&](int tile, unsigned short* dst, int half) {
        const unsigned short* g = Ath + (size_t)half * (128 * K) + tile * 64;
        unsigned short* d = dst + half * 8192 + tid * 8;
        GLOAD16(g, d);
        GLOAD16(g + (size_t)64 * K, d + 4096);
    };
    auto stageB = [&](int tile, unsigned short* dst, int half) {
        const unsigned short* g = Bth + (size_t)half * (128 * K) + tile * 64;
        unsigned short* d = dst + half * 8192 + tid * 8;
        GLOAD16(g, d);
        GLOAD16(g + (size_t)64 * K, d + 4096);
    };

    stageB(0, B0lds, 0);
    stageB(0, B0lds, 1);
    stageA(0, A0lds, 0);
    stageA(0, A0lds, 1);
    stageB(1, B1lds, 0);
    stageB(1, B1lds, 1);
    asm volatile("s_waitcnt vmcnt(4)" ::: "memory");
    __builtin_amdgcn_s_barrier();

#pragma unroll 1
    for (int t = 0; t < NT / 2 - 1; ++t) {
        const int v = 2 * t + 1, u2 = 2 * t + 2, v2 = 2 * t + 3;
        GEMM_BODY(1)
    }
    {
        const int t = NT / 2 - 1;
        const int v = 2 * t + 1, u2 = 2 * t + 2, v2 = 2 * t + 3;
        (void)u2; (void)v2;
        GEMM_BODY(0)
    }

    // ---- epilogue: relu+bias, PERMUTED t1 store -> one 8-B uint2 per (mf,qq) ----
    float bv[4];
#pragma unroll
    for (int nf = 0; nf < 4; ++nf) bv[nf] = bias[n0 + wn * 64 + nf * 16 + lr];

#pragma unroll
    for (int mf = 0; mf < 8; ++mf) {
#pragma unroll
        for (int qq = 0; qq < 4; ++qq) {
            long row = (long)arow0 + wm * 128 + mf * 16 + lq * 4 + qq;
            unsigned short o0 = f2bf(fmaxf(acc[mf][0][qq] + bv[0], 0.f));
            unsigned short o1 = f2bf(fmaxf(acc[mf][1][qq] + bv[1], 0.f));
            unsigned short o2 = f2bf(fmaxf(acc[mf][2][qq] + bv[2], 0.f));
            unsigned short o3 = f2bf(fmaxf(acc[mf][3][qq] + bv[3], 0.f));
            uint2 pk;
            pk.x = (unsigned)o0 | ((unsigned)o1 << 16);
            pk.y = (unsigned)o2 | ((unsigned)o3 << 16);
            *(uint2*)(&Cbf[(size_t)row * NC + n0 + wn * 64 + lr * 4]) = pk;
        }
    }
}

// ---------- FFN2 + LN2 fused: y = LN(t1 @ W2^T + bW2 + h) ----------
// BM=128 x BN=512, 8 waves (2m x 4n), balanced phases; un-pinned MFMA clusters.

#define RD_A2(Al) \
    areg[0][0] = *(const short8*)((Al) + aoffs2[0] + kk2[0]); \
    areg[0][1] = *(const short8*)((Al) + aoffs2[0] + kk2[1]); \
    areg[1][0] = *(const short8*)((Al) + aoffs2[1] + kk2[0]); \
    areg[1][1] = *(const short8*)((Al) + aoffs2[1] + kk2[1]); \
    areg[2][0] = *(const short8*)((Al) + aoffs2[2] + kk2[0]); \
    areg[2][1] = *(const short8*)((Al) + aoffs2[2] + kk2[1]); \
    areg[3][0] = *(const short8*)((Al) + aoffs2[3] + kk2[0]); \
    areg[3][1] = *(const short8*)((Al) + aoffs2[3] + kk2[1]);

#define RD_B2(Bl, q) \
    bq00 = *(const short8*)((Bl) + boffs2[2*(q)]   + kk2[0]); \
    bq01 = *(const short8*)((Bl) + boffs2[2*(q)]   + kk2[1]); \
    bq10 = *(const short8*)((Bl) + boffs2[2*(q)+1] + kk2[0]); \
    bq11 = *(const short8*)((Bl) + boffs2[2*(q)+1] + kk2[1]);

#define MM_Q2(q) \
    __builtin_amdgcn_s_setprio(1); \
    _Pragma("unroll") \
    for (int mf = 0; mf < 4; ++mf) { \
        acc[mf][2*(q)]   = mfma16(areg[mf][0], bq00, acc[mf][2*(q)]); \
        acc[mf][2*(q)]   = mfma16(areg[mf][1], bq01, acc[mf][2*(q)]); \
        acc[mf][2*(q)+1] = mfma16(areg[mf][0], bq10, acc[mf][2*(q)+1]); \
        acc[mf][2*(q)+1] = mfma16(areg[mf][1], bq11, acc[mf][2*(q)+1]); \
    } \
    __builtin_amdgcn_s_setprio(0);

#define BAR2 __builtin_amdgcn_s_barrier();

#define BODY2(MORE) \
        RD_B2(B0l, 0) \
        RD_A2(A0l) \
        stageB(v, B1l, 0); \
        MM_Q2(0) BAR2 \
        RD_B2(B0l, 1) \
        stageB(v, B1l, 1); \
        if (MORE) stageA(u2, A0l); \
        MM_Q2(1) BAR2 \
        RD_B2(B0l, 2) \
        MM_Q2(2) BAR2 \
        RD_B2(B0l, 3) \
        MM_Q2(3) \
        if (MORE) { asm volatile("s_waitcnt vmcnt(2)" ::: "memory"); } \
        else      { asm volatile("s_waitcnt vmcnt(0)" ::: "memory"); } \
        BAR2 \
        RD_B2(B1l, 0) \
        RD_A2(A1l) \
        if (MORE) stageB(u2, B0l, 0); \
        MM_Q2(0) BAR2 \
        RD_B2(B1l, 1) \
        if (MORE) { stageB(u2, B0l, 1); stageA(v2, A1l); } \
        MM_Q2(1) BAR2 \
        RD_B2(B1l, 2) \
        MM_Q2(2) BAR2 \
        RD_B2(B1l, 3) \
        MM_Q2(3) \
        if (MORE) { asm volatile("s_waitcnt vmcnt(2)" ::: "memory"); } \
        else      { asm volatile("s_waitcnt vmcnt(0)" ::: "memory"); } \
        BAR2

__global__ __launch_bounds__(512, 2) void gemm2ln_kernel(
    const unsigned short* __restrict__ A,      // t1 chunk [rows][2048] (perm-k)
    const unsigned short* __restrict__ Bw,     // W2T [512][2048] (perm-k)
    const float* __restrict__ bias,            // bW2
    const unsigned short* __restrict__ hres,   // h bf16 (full, global rows)
    const float* __restrict__ g2, const float* __restrict__ b2,
    float* __restrict__ y, long out_row0) {
    constexpr int K = 2048;
    constexpr int NT = K / 64;                 // 32 K-tiles

    extern __shared__ unsigned short lds[];
    unsigned short* A0l = lds;                 // [128][64]
    unsigned short* A1l = lds + 8192;
    unsigned short* B0l = lds + 16384;         // [512][64]
    unsigned short* B1l = lds + 49152;

    const int nwg = (int)gridDim.x;
    const int orig = (int)blockIdx.x;
    const int q8 = nwg >> 3, r8 = nwg & 7;
    const int xcd = orig & 7, idx = orig >> 3;
    const int w = (xcd < r8 ? xcd * (q8 + 1) : r8 * (q8 + 1) + (xcd - r8) * q8) + idx;
    const size_t arow0 = (size_t)w * 128;

    const int tid = threadIdx.x;
    const int l = tid & 63, wv = tid >> 6;
    const int wm = wv & 1, wn = wv >> 1;       // 2 m-waves x 4 n-waves
    const int lr = l & 15, lq = l >> 4;

    const int srow = tid >> 3;
    const int skb = ((((tid & 7) << 4) ^ ((srow & 7) << 4)) >> 1);

    const int sw = (lr & 7) << 4;
    int kk2[2];
    kk2[0] = ((lq * 16) ^ sw) >> 1;
    kk2[1] = ((64 + lq * 16) ^ sw) >> 1;
    int aoffs2[4], boffs2[8];
#pragma unroll
    for (int mf = 0; mf < 4; ++mf) aoffs2[mf] = (wm * 64 + mf * 16 + lr) * 64;
#pragma unroll
    for (int nf = 0; nf < 8; ++nf) boffs2[nf] = (wn * 128 + nf * 16 + lr) * 64;

    f32x4 acc[4][8];
#pragma unroll
    for (int i = 0; i < 4; ++i)
#pragma unroll
        for (int j = 0; j < 8; ++j) acc[i][j] = (f32x4){0.f, 0.f, 0.f, 0.f};

    short8 areg[4][2];
    short8 bq00, bq01, bq10, bq11;

    const unsigned short* Ath = A + (arow0 + srow) * (size_t)K + skb;
    const unsigned short* Bth = Bw + (size_t)srow * K + skb;

    auto stageA = [&](int tile, unsigned short* dst) {
        const unsigned short* g = Ath + tile * 64;
        unsigned short* d = dst + tid * 8;
        GLOAD16(g, d);
        GLOAD16(g + (size_t)64 * K, d + 4096);
    };
    auto stageB = [&](int tile, unsigned short* dst, int half) {
        const unsigned short* g = Bth + (size_t)(half * 256) * K + tile * 64;
        unsigned short* d = dst + half * 16384 + tid * 8;
#pragma unroll
        for (int i = 0; i < 4; ++i)
            GLOAD16(g + (size_t)(64 * i) * K, d + 4096 * i);
    };

    // prologue: A(0)[2], B(0)h0[4], B(0)h1[4], A(1)[2]; wait 10 oldest -> vmcnt(2)
    stageA(0, A0l);
    stageB(0, B0l, 0);
    stageB(0, B0l, 1);
    stageA(1, A1l);
    asm volatile("s_waitcnt vmcnt(2)" ::: "memory");
    __builtin_amdgcn_s_barrier();

#pragma unroll 1
    for (int t = 0; t < NT / 2 - 1; ++t) {
        const int v = 2 * t + 1, u2 = 2 * t + 2, v2 = 2 * t + 3;
        BODY2(1)
    }
    {
        const int t = NT / 2 - 1;
        const int v = 2 * t + 1, u2 = 2 * t + 2, v2 = 2 * t + 3;
        (void)u2; (void)v2;
        BODY2(0)
    }

    // ---- epilogue: bias + bf16-h residual, row LN across block, write y ----
    float* red = (float*)lds;                  // [sum:4x128][sq:4x128] floats
    float bv2[8], gv2[8], bb2[8];
#pragma unroll
    for (int nf = 0; nf < 8; ++nf) {
        int col = wn * 128 + nf * 16 + lr;
        bv2[nf] = bias[col];
        gv2[nf] = g2[col];
        bb2[nf] = b2[col];
    }

#pragma unroll
    for (int mf = 0; mf < 4; ++mf) {
#pragma unroll
        for (int qq = 0; qq < 4; ++qq) {
            int lrow = wm * 64 + mf * 16 + lq * 4 + qq;
            long grow = out_row0 + (long)arow0 + lrow;
            const unsigned short* hr = hres + (size_t)grow * 512 + wn * 128 + lr;
            float s = 0.f, s2 = 0.f;
#pragma unroll
            for (int nf = 0; nf < 8; ++nf) {
                float z = acc[mf][nf][qq] + bv2[nf] + bf2f(hr[nf * 16]);
                acc[mf][nf][qq] = z;
                s += z;
                s2 += z * z;
            }
            s += __shfl_xor(s, 1, 16); s2 += __shfl_xor(s2, 1, 16);
            s += __shfl_xor(s, 2, 16); s2 += __shfl_xor(s2, 2, 16);
            s += __shfl_xor(s, 4, 16); s2 += __shfl_xor(s2, 4, 16);
            s += __shfl_xor(s, 8, 16); s2 += __shfl_xor(s2, 8, 16);
            if (lr == 0) {
                red[wn * 128 + lrow] = s;
                red[512 + wn * 128 + lrow] = s2;
            }
        }
    }
    __syncthreads();

#pragma unroll
    for (int mf = 0; mf < 4; ++mf) {
#pragma unroll
        for (int qq = 0; qq < 4; ++qq) {
            int lrow = wm * 64 + mf * 16 + lq * 4 + qq;
            long grow = out_row0 + (long)arow0 + lrow;
            float s = red[lrow] + red[128 + lrow] + red[256 + lrow] + red[384 + lrow];
            float s2 = red[512 + lrow] + red[640 + lrow] + red[768 + lrow] + red[896 + lrow];
            float mu = s * (1.f / 512.f);
            float var = s2 * (1.f / 512.f) - mu * mu;
            float inv = rsqrtf(var + 1e-5f);
            float* yr = y + (size_t)grow * 512 + wn * 128 + lr;
#pragma unroll
            for (int nf = 0; nf < 8; ++nf)
                yr[nf * 16] = (acc[mf][nf][qq] - mu) * inv * gv2[nf] + bb2[nf];
        }
    }
}

// ---------- host ----------
extern "C" void kernel_launch(void* const* d_in, const int* in_sizes, int n_in,
                              void* d_out, int out_size, void* d_ws, size_t ws_size,
                              hipStream_t stream) {
    const float* x = (const float*)d_in[0];
    const void* mask = d_in[1];
    const float* g1 = (const float*)d_in[2];
    const float* b1 = (const float*)d_in[3];
    const float* g2 = (const float*)d_in[4];
    const float* b2 = (const float*)d_in[5];
    const float* W1 = (const float*)d_in[6];
    const float* bW1 = (const float*)d_in[7];
    const float* W2 = (const float*)d_in[8];
    const float* bW2 = (const float*)d_in[9];

    float* y = (float*)d_out;
    float* attn = y + Y_ELEMS;
    char* ws = (char*)d_ws;
    unsigned short* W1T = (unsigned short*)(ws);                 // 2 MiB  [2048][512]
    unsigned short* W2T = (unsigned short*)(ws + 2097152);       // 2 MiB  [512][2048] perm-k
    int* flag = (int*)(ws + 4194304);
    unsigned short* h = (unsigned short*)(ws + 4194560);         // 64 MiB [65536][512] bf16
    unsigned short* t1 = (unsigned short*)(ws + 71303424ULL);    // [chunk*256][2048] bf16 perm-k

    hipFuncSetAttribute((const void*)gemm1_kernel,
                        hipFuncAttributeMaxDynamicSharedMemorySize, 131072);
    hipFuncSetAttribute((const void*)gemm2ln_kernel,
                        hipFuncAttributeMaxDynamicSharedMemorySize, 163840);

    // cap t1 chunk at 128 M-tiles (128 MiB): keeps the produce->consume window
    // L3-resident (t1 chunk + h < 256 MiB Infinity Cache) while staying
    // occupancy-neutral: gemm1 grid 1024 = 2 full 2-blocks/CU rounds,
    // gemm2ln grid 256 = 1 full 1-block/CU round per chunk.
    long cap256 = ((long)ws_size - 71303424L) / (256L * 2048L * 2L);
    if (cap256 < 1) cap256 = 1;
    if (cap256 > 128) cap256 = 128;

    transpose_kernel<<<dim3(64, 16), dim3(256), 0, stream>>>(W1, W1T, 512, 2048, 0);
    transpose_kernel<<<dim3(16, 64), dim3(256), 0, stream>>>(W2, W2T, 2048, 512, 1);
    detect_kernel<<<1, 256, 0, stream>>>((const unsigned char*)mask, flag);
    stage1_kernel<<<4096, 256, 0, stream>>>(x, (const unsigned char*)mask, (const int*)mask,
                                            flag, g1, b1, attn, h);
    for (long t0 = 0; t0 < 256; t0 += cap256) {
        long mt = (256 - t0 < cap256) ? (256 - t0) : cap256;
        long row0 = t0 * 256;
        gemm1_kernel<<<dim3((unsigned)(8 * mt)), 512, 131072, stream>>>(
            h + (size_t)row0 * 512, W1T, bW1, t1);
        gemm2ln_kernel<<<dim3((unsigned)(2 * mt)), 512, 163840, stream>>>(
            t1, W2T, bW2, h, g2, b2, y, row0);
    }
}